// Round 5
// baseline (2304.377 us; speedup 1.0000x reference)
//
#include <hip/hip_runtime.h>
#include <cfloat>
#include <cstdint>

#define F_FEAT 256
#define NHID 128
#define NCLASS 16
#define KTOP 5

#define BR 128
#define BC 128
#define NSPLIT 16
#define QCAP 448

typedef _Float16 f16x8 __attribute__((ext_vector_type(8)));
typedef __attribute__((ext_vector_type(4))) float f32x4;

// ---------------- helpers ----------------
__device__ __forceinline__ void topk_insert5(float (&v)[5], int (&ix)[5], float cv, int ci) {
  // rank order: (value desc, index asc)  -- matches jax.lax.top_k
  if (cv < v[4] || (cv == v[4] && ci > ix[4])) return;
  int pos = 0;
#pragma unroll
  for (int j = 0; j < 5; ++j) pos += ((v[j] > cv) || (v[j] == cv && ix[j] < ci)) ? 1 : 0;
  if (pos >= 5) return;
  for (int j = 4; j > pos; --j) { v[j] = v[j - 1]; ix[j] = ix[j - 1]; }
  v[pos] = cv; ix[pos] = ci;
}

// ---------------- graph prep ----------------
__global__ void k_deg_count(const int* __restrict__ ar, const float* __restrict__ av,
                            const int* __restrict__ nr, const float* __restrict__ nv,
                            float* deg_adj, float* deg_ned, int* cntA, int* cntN, int E) {
  int e = blockIdx.x * blockDim.x + threadIdx.x;
  if (e >= E) return;
  int ra = ar[e]; int rn = nr[e];
  atomicAdd(&deg_adj[ra], av[e]);
  atomicAdd(&deg_ned[rn], nv[e]);
  atomicAdd(&cntA[ra], 1);
  atomicAdd(&cntN[rn], 1);
}

__global__ __launch_bounds__(1024) void k_scan_pair(const int* c0, int* o0, const int* c1, int* o1, int n) {
  const int* c = (blockIdx.x == 0) ? c0 : c1;
  int* o = (blockIdx.x == 0) ? o0 : o1;
  if (c == nullptr) return;
  __shared__ int buf[1024];
  int tid = threadIdx.x;
  int base = 0;
  int chunks = (n + 1023) >> 10;
  for (int ch = 0; ch < chunks; ++ch) {
    int i = (ch << 10) + tid;
    buf[tid] = (i < n) ? c[i] : 0;
    __syncthreads();
    for (int offd = 1; offd < 1024; offd <<= 1) {
      int t = (tid >= offd) ? buf[tid - offd] : 0;
      __syncthreads();
      buf[tid] += t;
      __syncthreads();
    }
    if (i < n) o[i + 1] = base + buf[tid];
    int tot = buf[1023];
    __syncthreads();
    base += tot;
  }
  if (tid == 0) o[0] = 0;
}

__global__ void k_rs(const float* deg_adj, const float* deg_ned, float* rs_adj, float* rinv_ned, int N) {
  int i = blockIdx.x * blockDim.x + threadIdx.x;
  if (i >= N) return;
  rs_adj[i] = 1.0f / (sqrtf(deg_adj[i]) + 1e-10f);
  rinv_ned[i] = 1.0f / (deg_ned[i] + 1e-10f);
}

__global__ void k_fill2(const int* ar, const int* nr, const int* rpA, const int* rpN,
                        int* fillA, int* fillN, int* permA, int* permN, int E) {
  int e = blockIdx.x * blockDim.x + threadIdx.x;
  if (e >= E) return;
  int ra = ar[e];
  permA[rpA[ra] + atomicAdd(&fillA[ra], 1)] = e;
  int rn = nr[e];
  permN[rpN[rn] + atomicAdd(&fillN[rn], 1)] = e;
}

__global__ void k_edgeval(const int* ar, const int* ac, const float* av,
                          const int* nr, const float* nv,
                          const float* rs_adj, const float* rinv_ned,
                          float* adj_sym, float* ned_rw, int E) {
  int e = blockIdx.x * blockDim.x + threadIdx.x;
  if (e >= E) return;
  adj_sym[e] = av[e] * rs_adj[ar[e]] * rs_adj[ac[e]];
  ned_rw[e] = nv[e] * rinv_ned[nr[e]];
}

// ---------------- SpMMs (CSR, block per row, feature per thread) ----------------
__global__ void k_spmm1(const int* __restrict__ rpA, const int* __restrict__ permA,
                        const int* __restrict__ ac, const float* __restrict__ adj_sym,
                        const float* __restrict__ x, const float* __restrict__ Wd1,
                        float* __restrict__ emb, int N) {
  int r = blockIdx.x; int f = threadIdx.x;
  int s = rpA[r], e = rpA[r + 1];
  float acc = 0.f;
  for (int i = s; i < e; ++i) {
    int id = permA[i];
    acc += adj_sym[id] * x[(size_t)ac[id] * F_FEAT + f];
  }
  emb[(size_t)r * F_FEAT + f] = tanhf(acc * Wd1[f]);
}

__global__ void k_spmm2_norm(const int* __restrict__ rpA, const int* __restrict__ permA,
                             const int* __restrict__ ac, const float* __restrict__ adj_sym,
                             const float* __restrict__ emb, const float* __restrict__ Wd2,
                             float* __restrict__ embn, int N) {
  __shared__ float red[F_FEAT];
  int r = blockIdx.x; int f = threadIdx.x;
  int s = rpA[r], e = rpA[r + 1];
  float acc = 0.f;
  for (int i = s; i < e; ++i) {
    int id = permA[i];
    acc += adj_sym[id] * emb[(size_t)ac[id] * F_FEAT + f];
  }
  float val = acc * Wd2[f];
  red[f] = val * val;
  __syncthreads();
  for (int st = F_FEAT / 2; st > 0; st >>= 1) {
    if (f < st) red[f] += red[f + st];
    __syncthreads();
  }
  float rinv = 1.0f / (sqrtf(red[0]) + 1e-12f);
  embn[(size_t)r * F_FEAT + f] = val * rinv;
}

__global__ void k_spmmT(const int* __restrict__ rpN, const int* __restrict__ permN,
                        const int* __restrict__ nc, const float* __restrict__ ned_rw,
                        const float* __restrict__ embn, float* __restrict__ Tm, int N) {
  int r = blockIdx.x; int f = threadIdx.x;
  int s = rpN[r], e = rpN[r + 1];
  float acc = 0.f;
  for (int i = s; i < e; ++i) {
    int id = permN[i];
    acc += ned_rw[id] * embn[(size_t)nc[id] * F_FEAT + f];
  }
  Tm[(size_t)r * F_FEAT + f] = acc;
}

// ---- exact 2-way fp16 split: src[N][256] f32 -> 2 planes [Npad][256] fp16 ----
__global__ void k_convert(const float* __restrict__ src,
                          unsigned short* __restrict__ p1, unsigned short* __restrict__ p2,
                          int N, int Npad) {
  int idx = blockIdx.x * blockDim.x + threadIdx.x;   // one thread per 4 elems
  int total = Npad * (F_FEAT / 4);
  if (idx >= total) return;
  int row = idx >> 6;
  int c4 = (idx & 63) << 2;
  float4 v = make_float4(0.f, 0.f, 0.f, 0.f);
  if (row < N) v = *reinterpret_cast<const float4*>(src + (size_t)row * F_FEAT + c4);
  float arr[4] = {v.x, v.y, v.z, v.w};
  ushort4 o1, o2;
  unsigned short* q1 = (unsigned short*)&o1;
  unsigned short* q2 = (unsigned short*)&o2;
#pragma unroll
  for (int j = 0; j < 4; ++j) {
    float a = arr[j];
    _Float16 h1 = (_Float16)a;
    float r = a - (float)h1;      // exact
    _Float16 h2 = (_Float16)r;    // residual of residual <= 2^-22 |a|: dropped
    q1[j] = __builtin_bit_cast(unsigned short, h1);
    q2[j] = __builtin_bit_cast(unsigned short, h2);
  }
  size_t off = (size_t)row * F_FEAT + c4;
  *reinterpret_cast<ushort4*>(p1 + off) = o1;
  *reinterpret_cast<ushort4*>(p2 + off) = o2;
}

// ---- fused MFMA GEMM (T @ embn^T, f32-faithful via 3 fp16 products) + top-5 ----
// Register-prefetch pipeline: global->reg loads for slab s+1 issued before the
// MFMA phase of slab s; ds_write applies swizzle on the write side.
// LDS layout (per plane, [128 rows][4 slots of 16B]): slot s of row r stored at
// physical slot s ^ (((r&15)>>1)&3)  -- identical layout to R4's verified one.
__global__ __launch_bounds__(256, 3) void k_gemm_topk(
    const unsigned short* __restrict__ A1, const unsigned short* __restrict__ A2,
    const unsigned short* __restrict__ B1, const unsigned short* __restrict__ B2,
    float* __restrict__ pv, int* __restrict__ pi, int N, int colTiles) {
  __shared__ __align__(16) unsigned short planes[4 * 4096];  // 4 planes x 8KB
  float* scan = (float*)planes;                              // fullscan aliases planes
  __shared__ float thr[BR];
  __shared__ float qv[QCAP];
  __shared__ unsigned qm[QCAP];
  __shared__ int qcnt;

  int tid = threadIdx.x;
  int lane = tid & 63;
  int wid = tid >> 6;
  int wr = wid >> 1, wc = wid & 1;
  int lr = lane & 15;   // row/col within 16-block
  int lg = lane >> 4;   // k-group (8 fp16 each)
  int row0 = blockIdx.x * BR;
  int per = (colTiles + NSPLIT - 1) / NSPLIT;
  int ct0 = blockIdx.y * per;
  int ct1 = min(ct0 + per, colTiles);

  // staging: wave w owns plane w. lane covers row (lane>>2)+16i, 16B slot lane&3.
  const unsigned short* pg = (wid == 0) ? A1 : (wid == 1) ? A2 : (wid == 2) ? B1 : B2;
  int srow = lane >> 2;                        // row within 16-row group
  int sslot = lane & 3;                        // linear global 16B slot
  int skey = (lane >> 3) & 3;                  // ((row&15)>>1)&3
  char* lwr = (char*)planes + wid * 8192 + srow * 64 + ((sslot ^ skey) * 16);
  const char* gtb = (const char*)pg + ((size_t)srow << 9) + sslot * 16;
  bool isA = (wid < 2);
  // read-side physical slot for fragments (unchanged from R4)
  int fslot = (lg ^ ((lr >> 1) & 3)) * 8;      // ushort offset of 16B unit

  float bv[5]; int bi[5];
#pragma unroll
  for (int k = 0; k < 5; ++k) { bv[k] = -FLT_MAX; bi[k] = 0x7fffffff; }
  if (tid < BR) thr[tid] = -FLT_MAX;
  if (tid == 0) qcnt = 0;
  __syncthreads();

  float4 pf[8];
  {
    size_t tb = ((size_t)(isA ? row0 : ct0 * BC) << 9);
#pragma unroll
    for (int i = 0; i < 8; ++i)
      pf[i] = *reinterpret_cast<const float4*>(gtb + tb + (size_t)i * 8192);
  }

  for (int ct = ct0; ct < ct1; ++ct) {
    int col0 = ct * BC;

    f32x4 acc[4][4];
#pragma unroll
    for (int m = 0; m < 4; ++m)
#pragma unroll
      for (int n = 0; n < 4; ++n) acc[m][n] = (f32x4){0.f, 0.f, 0.f, 0.f};

    for (int ks = 0; ks < 8; ++ks) {
      __syncthreads();   // all waves done reading LDS for previous slab
#pragma unroll
      for (int i = 0; i < 8; ++i)
        *reinterpret_cast<float4*>(lwr + i * 1024) = pf[i];
      // issue next slab's loads (cross col-tile boundary); latency hides under MFMA
      {
        int nks = ks + 1, nct = ct;
        if (nks == 8) { nks = 0; ++nct; }
        if (nct < ct1) {
          size_t tb = ((size_t)(isA ? row0 : nct * BC) << 9) + (size_t)nks * 64;
#pragma unroll
          for (int i = 0; i < 8; ++i)
            pf[i] = *reinterpret_cast<const float4*>(gtb + tb + (size_t)i * 8192);
        }
      }
      __syncthreads();   // staged slab visible

      // ---- fragments + 3-product MFMA
      f16x8 fb[2][4];
#pragma unroll
      for (int n = 0; n < 4; ++n) {
        int crow = wc * 64 + n * 16 + lr;
        int ro = crow * 32 + fslot;
        fb[0][n] = *reinterpret_cast<const f16x8*>(planes + 2 * 4096 + ro);
        fb[1][n] = *reinterpret_cast<const f16x8*>(planes + 3 * 4096 + ro);
      }
#pragma unroll
      for (int m = 0; m < 4; ++m) {
        int arow = wr * 64 + m * 16 + lr;
        int ro = arow * 32 + fslot;
        f16x8 fa1 = *reinterpret_cast<const f16x8*>(planes + 0 * 4096 + ro);
        f16x8 fa2 = *reinterpret_cast<const f16x8*>(planes + 1 * 4096 + ro);
#pragma unroll
        for (int n = 0; n < 4; ++n) {
          acc[m][n] = __builtin_amdgcn_mfma_f32_16x16x32_f16(fa1, fb[1][n], acc[m][n], 0, 0, 0);
          acc[m][n] = __builtin_amdgcn_mfma_f32_16x16x32_f16(fa2, fb[0][n], acc[m][n], 0, 0, 0);
          acc[m][n] = __builtin_amdgcn_mfma_f32_16x16x32_f16(fa1, fb[0][n], acc[m][n], 0, 0, 0);
        }
      }
    }

    // ---- top-k: threshold queue (ballot-compacted), fullscan fallback
    bool first = (ct == ct0);
    if (!first) {
#pragma unroll
      for (int m = 0; m < 4; ++m) {
#pragma unroll
        for (int rg = 0; rg < 4; ++rg) {
          int rl = wr * 64 + m * 16 + lg * 4 + rg;   // row within 128-tile
          float trr = thr[rl];
          bool rok = (row0 + rl) < N;
#pragma unroll
          for (int n = 0; n < 4; ++n) {
            float vv = acc[m][n][rg];
            int c = col0 + wc * 64 + n * 16 + lr;
            bool p = rok && (c < N) && (vv >= trr);
            unsigned long long mk = __ballot(p);
            if (mk != 0ull) {
              int leader = __ffsll((long long)mk) - 1;
              int base = 0;
              if (lane == leader) base = atomicAdd(&qcnt, __popcll(mk));
              base = __shfl(base, leader, 64);
              if (p) {
                int pos = base + __popcll(mk & ((1ull << lane) - 1ull));
                if (pos < QCAP) {
                  qv[pos] = vv;
                  qm[pos] = ((unsigned)c << 7) | (unsigned)rl;
                }
              }
            }
          }
        }
      }
    }
    __syncthreads();
    int qn = qcnt;
    bool fullscan = first || (qn > QCAP);
    if (!fullscan) {
      if (tid < BR) {
        for (int i = 0; i < qn; ++i) {
          unsigned m = qm[i];
          if ((int)(m & 127u) == tid) topk_insert5(bv, bi, qv[i], (int)(m >> 7));
        }
      }
    } else {
      // 4 passes of 32 rows via scan buffer [32][132] (aliases plane LDS)
      for (int p = 0; p < 4; ++p) {
        __syncthreads();
        if (wr == (p >> 1)) {
          int mlo = (p & 1) * 2;
#pragma unroll
          for (int mm = 0; mm < 2; ++mm) {
            int m = mlo + mm;
#pragma unroll
            for (int rg = 0; rg < 4; ++rg) {
              int rsc = m * 16 + lg * 4 + rg - (p & 1) * 32;   // 0..31
#pragma unroll
              for (int n = 0; n < 4; ++n)
                scan[rsc * 132 + wc * 64 + n * 16 + lr] = acc[m][n][rg];
            }
          }
        }
        __syncthreads();
        int rloc = tid - 32 * p;
        if (rloc >= 0 && rloc < 32) {
          for (int cdx = 0; cdx < BC; ++cdx) {
            int gc = col0 + cdx;
            if (gc < N) topk_insert5(bv, bi, scan[rloc * 132 + cdx], gc);
          }
        }
      }
      __syncthreads();
    }
    __syncthreads();
    if (tid < BR) thr[tid] = bv[4];
    if (tid == 0) qcnt = 0;
    __syncthreads();
  }

  if (tid < BR) {
    int r = row0 + tid;
    if (r < N) {
      size_t baseo = ((size_t)r * NSPLIT + blockIdx.y) * 5;
#pragma unroll
      for (int k = 0; k < 5; ++k) { pv[baseo + k] = bv[k]; pi[baseo + k] = bi[k]; }
    }
  }
}

// ---------------- merge partial top-5, build new degrees/counts ----------------
__global__ void k_merge(const float* __restrict__ pv, const int* __restrict__ pi,
                        float* __restrict__ topv, int* __restrict__ topi,
                        const float* deg_adj, float* deg_new, const int* cntA, int* cnt_new, int N) {
  int r = blockIdx.x * blockDim.x + threadIdx.x;
  if (r >= N) return;
  float v[5]; int ix[5];
#pragma unroll
  for (int k = 0; k < 5; ++k) { v[k] = -FLT_MAX; ix[k] = 0x7fffffff; }
  size_t base = (size_t)r * NSPLIT * 5;
  for (int s = 0; s < NSPLIT; ++s)
    for (int k = 0; k < 5; ++k)
      topk_insert5(v, ix, pv[base + s * 5 + k], pi[base + s * 5 + k]);
  float sumv = 0.f;
  for (int k = 0; k < 5; ++k) {
    topv[(size_t)r * 5 + k] = v[k];
    topi[(size_t)r * 5 + k] = ix[k];
    sumv += v[k];
    atomicAdd(&deg_new[ix[k]], v[k]);
    atomicAdd(&cnt_new[ix[k]], 1);
  }
  atomicAdd(&deg_new[r], deg_adj[r] + sumv);
  atomicAdd(&cnt_new[r], cntA[r] + KTOP);
}

__global__ void k_rs_new(const float* deg_new, float* rs_new, int N) {
  int i = blockIdx.x * blockDim.x + threadIdx.x;
  if (i >= N) return;
  rs_new[i] = 1.0f / (sqrtf(deg_new[i]) + 1e-10f);
}

__global__ void k_fill_new(const int* ar, const int* topi, const int* rp_new, int* fill_new,
                           int* perm_new, int E, int NK, int total) {
  int t = blockIdx.x * blockDim.x + threadIdx.x;
  if (t >= total) return;
  int r;
  if (t < E) r = ar[t];
  else if (t < E + NK) r = (t - E) / KTOP;
  else r = topi[t - E - NK];
  perm_new[rp_new[r] + atomicAdd(&fill_new[r], 1)] = t;
}

// ---------------- dense layers ----------------
__global__ void k_xw1(const float* __restrict__ x, const float* __restrict__ W1,
                      float* __restrict__ XW1, int N) {
  int c = threadIdx.x & 127;
  int half = threadIdx.x >> 7;
  int r0 = blockIdx.x * 8 + half * 4;
  int rm = N - 1;
  const float* x0 = x + (size_t)min(r0 + 0, rm) * F_FEAT;
  const float* x1 = x + (size_t)min(r0 + 1, rm) * F_FEAT;
  const float* x2 = x + (size_t)min(r0 + 2, rm) * F_FEAT;
  const float* x3 = x + (size_t)min(r0 + 3, rm) * F_FEAT;
  float a0 = 0.f, a1 = 0.f, a2 = 0.f, a3 = 0.f;
  for (int k = 0; k < F_FEAT; ++k) {
    float wv = W1[k * NHID + c];
    a0 += x0[k] * wv; a1 += x1[k] * wv; a2 += x2[k] * wv; a3 += x3[k] * wv;
  }
  if (r0 + 0 < N) XW1[(size_t)(r0 + 0) * NHID + c] = a0;
  if (r0 + 1 < N) XW1[(size_t)(r0 + 1) * NHID + c] = a1;
  if (r0 + 2 < N) XW1[(size_t)(r0 + 2) * NHID + c] = a2;
  if (r0 + 3 < N) XW1[(size_t)(r0 + 3) * NHID + c] = a3;
}

__global__ void k_spmm_h(const int* __restrict__ rp, const int* __restrict__ perm,
                         const int* __restrict__ ac, const float* __restrict__ av,
                         const int* __restrict__ topi, const float* __restrict__ topv,
                         const float* __restrict__ rs, const float* __restrict__ XW1,
                         const float* __restrict__ b1, float* __restrict__ h,
                         int N, int E, int NK) {
  int r = blockIdx.x; int f = threadIdx.x;  // 128 threads
  int s = rp[r], e = rp[r + 1];
  float acc = 0.f;
  for (int i = s; i < e; ++i) {
    int id = perm[i];
    int c; float v;
    if (id < E) { c = ac[id]; v = av[id]; }
    else if (id < E + NK) { int q = id - E; c = topi[q]; v = topv[q]; }
    else { int q = id - E - NK; c = q / KTOP; v = topv[q]; }
    acc += v * rs[c] * XW1[(size_t)c * NHID + f];
  }
  float o = rs[r] * acc + b1[f];
  h[(size_t)r * NHID + f] = fmaxf(o, 0.f);
}

__global__ void k_hw2(const float* __restrict__ h, const float* __restrict__ W2,
                      float* __restrict__ HW2, int N) {
  int tid = threadIdx.x;
  int rr = tid >> 4, c = tid & 15;
  int r = blockIdx.x * 16 + rr;
  if (r >= N) return;
  float acc = 0.f;
  for (int k = 0; k < NHID; ++k) acc += h[(size_t)r * NHID + k] * W2[k * NCLASS + c];
  HW2[(size_t)r * NCLASS + c] = acc;
}

__global__ void k_spmm_out(const int* __restrict__ rp, const int* __restrict__ perm,
                           const int* __restrict__ ac, const float* __restrict__ av,
                           const int* __restrict__ topi, const float* __restrict__ topv,
                           const float* __restrict__ rs, const float* __restrict__ HW2,
                           const float* __restrict__ b2, float* __restrict__ out,
                           int N, int E, int NK) {
  int tid = threadIdx.x;
  int rr = tid >> 4, c = tid & 15;
  int r = blockIdx.x * 16 + rr;
  if (r >= N) return;
  int s = rp[r], e = rp[r + 1];
  float acc = 0.f;
  for (int i = s; i < e; ++i) {
    int id = perm[i];
    int cc; float v;
    if (id < E) { cc = ac[id]; v = av[id]; }
    else if (id < E + NK) { int q = id - E; cc = topi[q]; v = topv[q]; }
    else { int q = id - E - NK; cc = q / KTOP; v = topv[q]; }
    acc += v * rs[cc] * HW2[(size_t)cc * NCLASS + c];
  }
  out[(size_t)r * NCLASS + c] = rs[r] * acc + b2[c];
}

// ---------------- host ----------------
extern "C" void kernel_launch(void* const* d_in, const int* in_sizes, int n_in,
                              void* d_out, int out_size, void* d_ws, size_t ws_size,
                              hipStream_t stream) {
  (void)n_in; (void)out_size; (void)ws_size;
  const float* x   = (const float*)d_in[0];
  const int*   ar  = (const int*)d_in[1];
  const int*   ac  = (const int*)d_in[2];
  const float* av  = (const float*)d_in[3];
  const int*   nr  = (const int*)d_in[4];
  const int*   nc  = (const int*)d_in[5];
  const float* nv  = (const float*)d_in[6];
  const float* Wd1 = (const float*)d_in[7];
  const float* Wd2 = (const float*)d_in[8];
  const float* W1  = (const float*)d_in[9];
  const float* b1  = (const float*)d_in[10];
  const float* W2  = (const float*)d_in[11];
  const float* b2  = (const float*)d_in[12];
  int N = in_sizes[0] / F_FEAT;
  int E = in_sizes[3];
  int NK = N * KTOP;
  int total_new = E + 2 * NK;
  int Npad = ((N + 127) / 128) * 128;

  char* w = (char*)d_ws;
  size_t off = 0;
  auto carveB = [&](size_t bytes) -> void* {
    void* p = (void*)(w + off);
    off += (bytes + 255) & ~((size_t)255);
    return p;
  };
  auto carve = [&](size_t elems) -> void* { return carveB(elems * 4); };
  size_t zstart = off;
  float* deg_adj = (float*)carve(N);
  float* deg_ned = (float*)carve(N);
  float* deg_new = (float*)carve(N);
  int* cntA = (int*)carve(N);
  int* cntN = (int*)carve(N);
  int* cnt_new = (int*)carve(N);
  int* fillA = (int*)carve(N);
  int* fillN = (int*)carve(N);
  int* fill_new = (int*)carve(N);
  size_t zbytes = off - zstart;
  float* rs_adj = (float*)carve(N);
  float* rinv_ned = (float*)carve(N);
  float* rs_new = (float*)carve(N);
  float* adj_sym = (float*)carve(E);
  float* ned_rw = (float*)carve(E);
  int* rpA = (int*)carve(N + 1);
  int* rpN = (int*)carve(N + 1);
  int* rp_new = (int*)carve(N + 1);
  int* permA = (int*)carve(E);
  int* permN = (int*)carve(E);
  int* perm_new = (int*)carve(total_new);
  float* emb  = (float*)carve((size_t)N * F_FEAT);
  float* embn = (float*)carve((size_t)N * F_FEAT);
  float* Tm   = (float*)carve((size_t)N * F_FEAT);
  float* topv = (float*)carve(NK);
  int*   topi = (int*)carve(NK);
  float* pv = (float*)carve((size_t)N * NSPLIT * 5);
  int*   pi = (int*)carve((size_t)N * NSPLIT * 5);
  float* XW1  = (float*)carve((size_t)N * NHID);
  float* hbuf = (float*)carve((size_t)N * NHID);
  float* HW2  = (float*)carve((size_t)N * NCLASS);
  size_t planeBytes = (size_t)Npad * F_FEAT * 2;
  unsigned short* TA1 = (unsigned short*)carveB(planeBytes);
  unsigned short* TA2 = (unsigned short*)carveB(planeBytes);
  unsigned short* EB1 = (unsigned short*)carveB(planeBytes);
  unsigned short* EB2 = (unsigned short*)carveB(planeBytes);

  hipMemsetAsync(w + zstart, 0, zbytes, stream);

  int eb = (E + 255) / 256;
  k_deg_count<<<eb, 256, 0, stream>>>(ar, av, nr, nv, deg_adj, deg_ned, cntA, cntN, E);
  k_scan_pair<<<2, 1024, 0, stream>>>(cntA, rpA, cntN, rpN, N);
  k_rs<<<(N + 255) / 256, 256, 0, stream>>>(deg_adj, deg_ned, rs_adj, rinv_ned, N);
  k_fill2<<<eb, 256, 0, stream>>>(ar, nr, rpA, rpN, fillA, fillN, permA, permN, E);
  k_edgeval<<<eb, 256, 0, stream>>>(ar, ac, av, nr, nv, rs_adj, rinv_ned, adj_sym, ned_rw, E);
  k_spmm1<<<N, F_FEAT, 0, stream>>>(rpA, permA, ac, adj_sym, x, Wd1, emb, N);
  k_spmm2_norm<<<N, F_FEAT, 0, stream>>>(rpA, permA, ac, adj_sym, emb, Wd2, embn, N);
  k_spmmT<<<N, F_FEAT, 0, stream>>>(rpN, permN, nc, ned_rw, embn, Tm, N);
  int cvb = (Npad * (F_FEAT / 4) + 255) / 256;
  k_convert<<<cvb, 256, 0, stream>>>(Tm, TA1, TA2, N, Npad);
  k_convert<<<cvb, 256, 0, stream>>>(embn, EB1, EB2, N, Npad);
  int colTiles = (N + BC - 1) / BC;
  dim3 gg((N + BR - 1) / BR, NSPLIT);
  k_gemm_topk<<<gg, 256, 0, stream>>>(TA1, TA2, EB1, EB2, pv, pi, N, colTiles);
  k_merge<<<(N + 255) / 256, 256, 0, stream>>>(pv, pi, topv, topi, deg_adj, deg_new, cntA, cnt_new, N);
  k_scan_pair<<<1, 1024, 0, stream>>>(cnt_new, rp_new, nullptr, nullptr, N);
  k_rs_new<<<(N + 255) / 256, 256, 0, stream>>>(deg_new, rs_new, N);
  k_fill_new<<<(total_new + 255) / 256, 256, 0, stream>>>(ar, topi, rp_new, fill_new, perm_new, E, NK, total_new);
  k_xw1<<<(N + 7) / 8, 256, 0, stream>>>(x, W1, XW1, N);
  k_spmm_h<<<N, NHID, 0, stream>>>(rp_new, perm_new, ac, av, topi, topv, rs_new, XW1, b1, hbuf, N, E, NK);
  k_hw2<<<(N + 15) / 16, 256, 0, stream>>>(hbuf, W2, HW2, N);
  k_spmm_out<<<(N + 15) / 16, 256, 0, stream>>>(rp_new, perm_new, ac, av, topi, topv, rs_new, HW2, b2, (float*)d_out, N, E, NK);
}

// Round 6
// 1636.977 us; speedup vs baseline: 1.4077x; 1.4077x over previous
//
#include <hip/hip_runtime.h>
#include <cfloat>
#include <cstdint>

#define F_FEAT 256
#define NHID 128
#define NCLASS 16
#define KTOP 5

typedef _Float16 f16x8 __attribute__((ext_vector_type(8)));
typedef __attribute__((ext_vector_type(4))) float f32x4;

// ---------------- helpers ----------------
__device__ __forceinline__ void topk_insert5(float (&v)[5], int (&ix)[5], float cv, int ci) {
  // rank order: (value desc, index asc)  -- matches jax.lax.top_k
  if (cv < v[4] || (cv == v[4] && ci > ix[4])) return;
  int pos = 0;
#pragma unroll
  for (int j = 0; j < 5; ++j) pos += ((v[j] > cv) || (v[j] == cv && ix[j] < ci)) ? 1 : 0;
  if (pos >= 5) return;
  for (int j = 4; j > pos; --j) { v[j] = v[j - 1]; ix[j] = ix[j - 1]; }
  v[pos] = cv; ix[pos] = ci;
}

__device__ __forceinline__ void gload_lds16(const void* g, void* l) {
  __builtin_amdgcn_global_load_lds((const __attribute__((address_space(1))) void*)g,
                                   (__attribute__((address_space(3))) void*)l, 16, 0, 0);
}

// ---------------- graph prep ----------------
__global__ void k_deg_count(const int* __restrict__ ar, const float* __restrict__ av,
                            const int* __restrict__ nr, const float* __restrict__ nv,
                            float* deg_adj, float* deg_ned, int* cntA, int* cntN, int E) {
  int e = blockIdx.x * blockDim.x + threadIdx.x;
  if (e >= E) return;
  int ra = ar[e]; int rn = nr[e];
  atomicAdd(&deg_adj[ra], av[e]);
  atomicAdd(&deg_ned[rn], nv[e]);
  atomicAdd(&cntA[ra], 1);
  atomicAdd(&cntN[rn], 1);
}

__global__ __launch_bounds__(1024) void k_scan_pair(const int* c0, int* o0, const int* c1, int* o1, int n) {
  const int* c = (blockIdx.x == 0) ? c0 : c1;
  int* o = (blockIdx.x == 0) ? o0 : o1;
  if (c == nullptr) return;
  __shared__ int buf[1024];
  int tid = threadIdx.x;
  int base = 0;
  int chunks = (n + 1023) >> 10;
  for (int ch = 0; ch < chunks; ++ch) {
    int i = (ch << 10) + tid;
    buf[tid] = (i < n) ? c[i] : 0;
    __syncthreads();
    for (int offd = 1; offd < 1024; offd <<= 1) {
      int t = (tid >= offd) ? buf[tid - offd] : 0;
      __syncthreads();
      buf[tid] += t;
      __syncthreads();
    }
    if (i < n) o[i + 1] = base + buf[tid];
    int tot = buf[1023];
    __syncthreads();
    base += tot;
  }
  if (tid == 0) o[0] = 0;
}

__global__ void k_rs(const float* deg_adj, const float* deg_ned, float* rs_adj, float* rinv_ned, int N) {
  int i = blockIdx.x * blockDim.x + threadIdx.x;
  if (i >= N) return;
  rs_adj[i] = 1.0f / (sqrtf(deg_adj[i]) + 1e-10f);
  rinv_ned[i] = 1.0f / (deg_ned[i] + 1e-10f);
}

__global__ void k_fill2(const int* ar, const int* nr, const int* rpA, const int* rpN,
                        int* fillA, int* fillN, int* permA, int* permN, int E) {
  int e = blockIdx.x * blockDim.x + threadIdx.x;
  if (e >= E) return;
  int ra = ar[e];
  permA[rpA[ra] + atomicAdd(&fillA[ra], 1)] = e;
  int rn = nr[e];
  permN[rpN[rn] + atomicAdd(&fillN[rn], 1)] = e;
}

__global__ void k_edgeval(const int* ar, const int* ac, const float* av,
                          const int* nr, const float* nv,
                          const float* rs_adj, const float* rinv_ned,
                          float* adj_sym, float* ned_rw, int E) {
  int e = blockIdx.x * blockDim.x + threadIdx.x;
  if (e >= E) return;
  adj_sym[e] = av[e] * rs_adj[ar[e]] * rs_adj[ac[e]];
  ned_rw[e] = nv[e] * rinv_ned[nr[e]];
}

// ---------------- SpMMs (CSR, block per row, feature per thread) ----------------
__global__ void k_spmm1(const int* __restrict__ rpA, const int* __restrict__ permA,
                        const int* __restrict__ ac, const float* __restrict__ adj_sym,
                        const float* __restrict__ x, const float* __restrict__ Wd1,
                        float* __restrict__ emb, int N) {
  int r = blockIdx.x; int f = threadIdx.x;
  int s = rpA[r], e = rpA[r + 1];
  float acc = 0.f;
  for (int i = s; i < e; ++i) {
    int id = permA[i];
    acc += adj_sym[id] * x[(size_t)ac[id] * F_FEAT + f];
  }
  emb[(size_t)r * F_FEAT + f] = tanhf(acc * Wd1[f]);
}

__global__ void k_spmm2_norm(const int* __restrict__ rpA, const int* __restrict__ permA,
                             const int* __restrict__ ac, const float* __restrict__ adj_sym,
                             const float* __restrict__ emb, const float* __restrict__ Wd2,
                             float* __restrict__ embn, int N) {
  __shared__ float red[F_FEAT];
  int r = blockIdx.x; int f = threadIdx.x;
  int s = rpA[r], e = rpA[r + 1];
  float acc = 0.f;
  for (int i = s; i < e; ++i) {
    int id = permA[i];
    acc += adj_sym[id] * emb[(size_t)ac[id] * F_FEAT + f];
  }
  float val = acc * Wd2[f];
  red[f] = val * val;
  __syncthreads();
  for (int st = F_FEAT / 2; st > 0; st >>= 1) {
    if (f < st) red[f] += red[f + st];
    __syncthreads();
  }
  float rinv = 1.0f / (sqrtf(red[0]) + 1e-12f);
  embn[(size_t)r * F_FEAT + f] = val * rinv;
}

__global__ void k_spmmT(const int* __restrict__ rpN, const int* __restrict__ permN,
                        const int* __restrict__ nc, const float* __restrict__ ned_rw,
                        const float* __restrict__ embn, float* __restrict__ Tm, int N) {
  int r = blockIdx.x; int f = threadIdx.x;
  int s = rpN[r], e = rpN[r + 1];
  float acc = 0.f;
  for (int i = s; i < e; ++i) {
    int id = permN[i];
    acc += ned_rw[id] * embn[(size_t)nc[id] * F_FEAT + f];
  }
  Tm[(size_t)r * F_FEAT + f] = acc;
}

// ---- exact 2-way fp16 split: src[N][256] f32 -> 2 planes [Npad][256] fp16 ----
__global__ void k_convert(const float* __restrict__ src,
                          unsigned short* __restrict__ p1, unsigned short* __restrict__ p2,
                          int N, int Npad) {
  int idx = blockIdx.x * blockDim.x + threadIdx.x;   // one thread per 4 elems
  int total = Npad * (F_FEAT / 4);
  if (idx >= total) return;
  int row = idx >> 6;
  int c4 = (idx & 63) << 2;
  float4 v = make_float4(0.f, 0.f, 0.f, 0.f);
  if (row < N) v = *reinterpret_cast<const float4*>(src + (size_t)row * F_FEAT + c4);
  float arr[4] = {v.x, v.y, v.z, v.w};
  ushort4 o1, o2;
  unsigned short* q1 = (unsigned short*)&o1;
  unsigned short* q2 = (unsigned short*)&o2;
#pragma unroll
  for (int j = 0; j < 4; ++j) {
    float a = arr[j];
    _Float16 h1 = (_Float16)a;
    float r = a - (float)h1;      // exact
    _Float16 h2 = (_Float16)r;    // residual of residual <= 2^-22 |a|: dropped
    q1[j] = __builtin_bit_cast(unsigned short, h1);
    q2[j] = __builtin_bit_cast(unsigned short, h2);
  }
  size_t off = (size_t)row * F_FEAT + c4;
  *reinterpret_cast<ushort4*>(p1 + off) = o1;
  *reinterpret_cast<ushort4*>(p2 + off) = o2;
}

// ---- fused MFMA GEMM (T @ embn^T, f32-faithful via 3 fp16 products) + top-5 ----
// 256x256 tile, 8 waves (2 row-halves x 4 col-quarters), K=256 in 8 slabs of 32.
// Double-buffered global_load_lds staging (2-phase: issue next slab before compute).
// LDS per buffer: 4 planes x [256 rows][4 slots of 16B]; slot s of row r stored at
// physical slot s ^ (((r&15)>>1)&3); source address pre-swizzled to match.
__global__ __launch_bounds__(512, 2) void k_gemm_topk(
    const unsigned short* __restrict__ A1, const unsigned short* __restrict__ A2,
    const unsigned short* __restrict__ B1, const unsigned short* __restrict__ B2,
    float* __restrict__ pv, int* __restrict__ pi, int N, int nrt, int nct) {
  __shared__ __align__(16) unsigned short lds[2 * 4 * 256 * 32];   // 128 KB
  float* scan = (float*)lds;                                       // [256][66] after K-loop

  int tid = threadIdx.x;
  int lane = tid & 63;
  int wid = tid >> 6;        // 0..7
  int wr = wid >> 2;         // 0..1  row half (128 rows)
  int wc = wid & 3;          // 0..3  col quarter (64 cols)
  int lr = lane & 15;
  int lg = lane >> 4;

  // block -> (rt, ct): XCD supertile swizzle (bijective when nrt%8==0 && nct%8==0)
  int bid = blockIdx.x;
  int rt, ct;
  if (((nrt & 7) == 0) && ((nct & 7) == 0)) {
    int xcd = bid & 7, loc = bid >> 3;
    int rpx = nrt >> 3;                 // row-tiles per XCD
    int stc = loc / (rpx << 3);         // 8-wide col supertile index
    int rem = loc - stc * (rpx << 3);
    rt = xcd * rpx + (rem >> 3);
    ct = (stc << 3) + (rem & 7);
  } else {
    rt = bid / nct; ct = bid - rt * nct;
  }
  int row0 = rt * 256, col0 = ct * 256;

  // staging geometry: wave stages plane sp, half sh (128 rows = 8 x 1KB issues)
  int sp = wid >> 1, sh = wid & 1;
  const unsigned short* pg = (sp == 0) ? A1 : (sp == 1) ? A2 : (sp == 2) ? B1 : B2;
  int srow = lane >> 2;                         // 0..15
  int sslot = lane & 3;                         // linear 16B slot in LDS
  int sgslot = sslot ^ ((srow >> 1) & 3);       // pre-swizzled global slot
  int t0 = (sp < 2) ? row0 : col0;
  const char* gbase = (const char*)pg + ((size_t)(t0 + sh * 128 + srow) << 9) + sgslot * 16;
  char* lbase0 = (char*)lds + sp * 16384 + sh * 8192;   // wave-uniform

  int fslot = (lg ^ ((lr >> 1) & 3)) << 3;      // ushort offset of 16B unit (read side)

  f32x4 acc[8][4];
#pragma unroll
  for (int m = 0; m < 8; ++m)
#pragma unroll
    for (int n = 0; n < 4; ++n) acc[m][n] = (f32x4){0.f, 0.f, 0.f, 0.f};

  // prologue: stage slab 0 into buffer 0
#pragma unroll
  for (int i = 0; i < 8; ++i)
    gload_lds16(gbase + ((size_t)i << 13), lbase0 + (i << 10));
  __syncthreads();

  for (int ks = 0; ks < 8; ++ks) {
    int cur = ks & 1;
    if (ks < 7) {      // issue next slab into other buffer; latency hides under MFMA
      const char* g = gbase + (ks + 1) * 64;
      char* lb = lbase0 + ((cur ^ 1) << 16);
#pragma unroll
      for (int i = 0; i < 8; ++i)
        gload_lds16(g + ((size_t)i << 13), lb + (i << 10));
    }
    const unsigned short* bufp = lds + cur * 32768;   // ushort units
    f16x8 fb[2][4];
#pragma unroll
    for (int n = 0; n < 4; ++n) {
      int off = (wc * 64 + n * 16 + lr) * 32 + fslot;
      fb[0][n] = *reinterpret_cast<const f16x8*>(bufp + 2 * 8192 + off);
      fb[1][n] = *reinterpret_cast<const f16x8*>(bufp + 3 * 8192 + off);
    }
#pragma unroll
    for (int m = 0; m < 8; ++m) {
      int off = (wr * 128 + m * 16 + lr) * 32 + fslot;
      f16x8 fa1 = *reinterpret_cast<const f16x8*>(bufp + 0 * 8192 + off);
      f16x8 fa2 = *reinterpret_cast<const f16x8*>(bufp + 1 * 8192 + off);
#pragma unroll
      for (int n = 0; n < 4; ++n) {
        acc[m][n] = __builtin_amdgcn_mfma_f32_16x16x32_f16(fa1, fb[1][n], acc[m][n], 0, 0, 0);
        acc[m][n] = __builtin_amdgcn_mfma_f32_16x16x32_f16(fa2, fb[0][n], acc[m][n], 0, 0, 0);
        acc[m][n] = __builtin_amdgcn_mfma_f32_16x16x32_f16(fa1, fb[0][n], acc[m][n], 0, 0, 0);
      }
    }
    __syncthreads();   // reads of buf done (next iter overwrites) + staged loads drained
  }

  // ---- top-5 per row via 4 passes of 64 cols through scan buffer [256][66]
  float bv[5]; int bi[5];
#pragma unroll
  for (int k = 0; k < 5; ++k) { bv[k] = -FLT_MAX; bi[k] = 0x7fffffff; }

  for (int p = 0; p < 4; ++p) {
    if (wc == p) {
#pragma unroll
      for (int m = 0; m < 8; ++m)
#pragma unroll
        for (int rg = 0; rg < 4; ++rg) {
          int rsc = wr * 128 + m * 16 + lg * 4 + rg;
#pragma unroll
          for (int n = 0; n < 4; ++n)
            scan[rsc * 66 + n * 16 + lr] = acc[m][n][rg];
        }
    }
    __syncthreads();
    if (tid < 256) {
      int gcb = col0 + p * 64;
      const float* srow_p = scan + tid * 66;
      for (int cdx = 0; cdx < 64; ++cdx) {
        int gc = gcb + cdx;
        if (gc < N) topk_insert5(bv, bi, srow_p[cdx], gc);
      }
    }
    __syncthreads();
  }

  if (tid < 256) {
    int r = row0 + tid;
    if (r < N) {
      size_t baseo = ((size_t)r * nct + ct) * 5;
#pragma unroll
      for (int k = 0; k < 5; ++k) { pv[baseo + k] = bv[k]; pi[baseo + k] = bi[k]; }
    }
  }
}

// ---------------- merge partial top-5, build new degrees/counts ----------------
__global__ void k_merge(const float* __restrict__ pv, const int* __restrict__ pi,
                        float* __restrict__ topv, int* __restrict__ topi,
                        const float* deg_adj, float* deg_new, const int* cntA, int* cnt_new,
                        int N, int nct) {
  int r = blockIdx.x * blockDim.x + threadIdx.x;
  if (r >= N) return;
  float v[5]; int ix[5];
#pragma unroll
  for (int k = 0; k < 5; ++k) { v[k] = -FLT_MAX; ix[k] = 0x7fffffff; }
  size_t base = (size_t)r * nct * 5;
  for (int s = 0; s < nct; ++s) {
    float v0 = pv[base + s * 5];
    if (v0 < v[4]) continue;              // partial sorted desc: cannot contribute
    for (int k = 0; k < 5; ++k)
      topk_insert5(v, ix, pv[base + s * 5 + k], pi[base + s * 5 + k]);
  }
  float sumv = 0.f;
  for (int k = 0; k < 5; ++k) {
    topv[(size_t)r * 5 + k] = v[k];
    topi[(size_t)r * 5 + k] = ix[k];
    sumv += v[k];
    atomicAdd(&deg_new[ix[k]], v[k]);
    atomicAdd(&cnt_new[ix[k]], 1);
  }
  atomicAdd(&deg_new[r], deg_adj[r] + sumv);
  atomicAdd(&cnt_new[r], cntA[r] + KTOP);
}

__global__ void k_rs_new(const float* deg_new, float* rs_new, int N) {
  int i = blockIdx.x * blockDim.x + threadIdx.x;
  if (i >= N) return;
  rs_new[i] = 1.0f / (sqrtf(deg_new[i]) + 1e-10f);
}

__global__ void k_fill_new(const int* ar, const int* topi, const int* rp_new, int* fill_new,
                           int* perm_new, int E, int NK, int total) {
  int t = blockIdx.x * blockDim.x + threadIdx.x;
  if (t >= total) return;
  int r;
  if (t < E) r = ar[t];
  else if (t < E + NK) r = (t - E) / KTOP;
  else r = topi[t - E - NK];
  perm_new[rp_new[r] + atomicAdd(&fill_new[r], 1)] = t;
}

// ---------------- dense layers ----------------
__global__ void k_xw1(const float* __restrict__ x, const float* __restrict__ W1,
                      float* __restrict__ XW1, int N) {
  int c = threadIdx.x & 127;
  int half = threadIdx.x >> 7;
  int r0 = blockIdx.x * 8 + half * 4;
  int rm = N - 1;
  const float* x0 = x + (size_t)min(r0 + 0, rm) * F_FEAT;
  const float* x1 = x + (size_t)min(r0 + 1, rm) * F_FEAT;
  const float* x2 = x + (size_t)min(r0 + 2, rm) * F_FEAT;
  const float* x3 = x + (size_t)min(r0 + 3, rm) * F_FEAT;
  float a0 = 0.f, a1 = 0.f, a2 = 0.f, a3 = 0.f;
  for (int k = 0; k < F_FEAT; ++k) {
    float wv = W1[k * NHID + c];
    a0 += x0[k] * wv; a1 += x1[k] * wv; a2 += x2[k] * wv; a3 += x3[k] * wv;
  }
  if (r0 + 0 < N) XW1[(size_t)(r0 + 0) * NHID + c] = a0;
  if (r0 + 1 < N) XW1[(size_t)(r0 + 1) * NHID + c] = a1;
  if (r0 + 2 < N) XW1[(size_t)(r0 + 2) * NHID + c] = a2;
  if (r0 + 3 < N) XW1[(size_t)(r0 + 3) * NHID + c] = a3;
}

__global__ void k_spmm_h(const int* __restrict__ rp, const int* __restrict__ perm,
                         const int* __restrict__ ac, const float* __restrict__ av,
                         const int* __restrict__ topi, const float* __restrict__ topv,
                         const float* __restrict__ rs, const float* __restrict__ XW1,
                         const float* __restrict__ b1, float* __restrict__ h,
                         int N, int E, int NK) {
  int r = blockIdx.x; int f = threadIdx.x;  // 128 threads
  int s = rp[r], e = rp[r + 1];
  float acc = 0.f;
  for (int i = s; i < e; ++i) {
    int id = perm[i];
    int c; float v;
    if (id < E) { c = ac[id]; v = av[id]; }
    else if (id < E + NK) { int q = id - E; c = topi[q]; v = topv[q]; }
    else { int q = id - E - NK; c = q / KTOP; v = topv[q]; }
    acc += v * rs[c] * XW1[(size_t)c * NHID + f];
  }
  float o = rs[r] * acc + b1[f];
  h[(size_t)r * NHID + f] = fmaxf(o, 0.f);
}

__global__ void k_hw2(const float* __restrict__ h, const float* __restrict__ W2,
                      float* __restrict__ HW2, int N) {
  int tid = threadIdx.x;
  int rr = tid >> 4, c = tid & 15;
  int r = blockIdx.x * 16 + rr;
  if (r >= N) return;
  float acc = 0.f;
  for (int k = 0; k < NHID; ++k) acc += h[(size_t)r * NHID + k] * W2[k * NCLASS + c];
  HW2[(size_t)r * NCLASS + c] = acc;
}

__global__ void k_spmm_out(const int* __restrict__ rp, const int* __restrict__ perm,
                           const int* __restrict__ ac, const float* __restrict__ av,
                           const int* __restrict__ topi, const float* __restrict__ topv,
                           const float* __restrict__ rs, const float* __restrict__ HW2,
                           const float* __restrict__ b2, float* __restrict__ out,
                           int N, int E, int NK) {
  int tid = threadIdx.x;
  int rr = tid >> 4, c = tid & 15;
  int r = blockIdx.x * 16 + rr;
  if (r >= N) return;
  int s = rp[r], e = rp[r + 1];
  float acc = 0.f;
  for (int i = s; i < e; ++i) {
    int id = perm[i];
    int cc; float v;
    if (id < E) { cc = ac[id]; v = av[id]; }
    else if (id < E + NK) { int q = id - E; cc = topi[q]; v = topv[q]; }
    else { int q = id - E - NK; cc = q / KTOP; v = topv[q]; }
    acc += v * rs[cc] * HW2[(size_t)cc * NCLASS + c];
  }
  out[(size_t)r * NCLASS + c] = rs[r] * acc + b2[c];
}

// ---------------- host ----------------
extern "C" void kernel_launch(void* const* d_in, const int* in_sizes, int n_in,
                              void* d_out, int out_size, void* d_ws, size_t ws_size,
                              hipStream_t stream) {
  (void)n_in; (void)out_size; (void)ws_size;
  const float* x   = (const float*)d_in[0];
  const int*   ar  = (const int*)d_in[1];
  const int*   ac  = (const int*)d_in[2];
  const float* av  = (const float*)d_in[3];
  const int*   nr  = (const int*)d_in[4];
  const int*   nc  = (const int*)d_in[5];
  const float* nv  = (const float*)d_in[6];
  const float* Wd1 = (const float*)d_in[7];
  const float* Wd2 = (const float*)d_in[8];
  const float* W1  = (const float*)d_in[9];
  const float* b1  = (const float*)d_in[10];
  const float* W2  = (const float*)d_in[11];
  const float* b2  = (const float*)d_in[12];
  int N = in_sizes[0] / F_FEAT;
  int E = in_sizes[3];
  int NK = N * KTOP;
  int total_new = E + 2 * NK;
  int Npad = ((N + 255) / 256) * 256;
  int nrt = Npad / 256;
  int nct = nrt;

  char* w = (char*)d_ws;
  size_t off = 0;
  auto carveB = [&](size_t bytes) -> void* {
    void* p = (void*)(w + off);
    off += (bytes + 255) & ~((size_t)255);
    return p;
  };
  auto carve = [&](size_t elems) -> void* { return carveB(elems * 4); };
  size_t zstart = off;
  float* deg_adj = (float*)carve(N);
  float* deg_ned = (float*)carve(N);
  float* deg_new = (float*)carve(N);
  int* cntA = (int*)carve(N);
  int* cntN = (int*)carve(N);
  int* cnt_new = (int*)carve(N);
  int* fillA = (int*)carve(N);
  int* fillN = (int*)carve(N);
  int* fill_new = (int*)carve(N);
  size_t zbytes = off - zstart;
  float* rs_adj = (float*)carve(N);
  float* rinv_ned = (float*)carve(N);
  float* rs_new = (float*)carve(N);
  float* adj_sym = (float*)carve(E);
  float* ned_rw = (float*)carve(E);
  int* rpA = (int*)carve(N + 1);
  int* rpN = (int*)carve(N + 1);
  int* rp_new = (int*)carve(N + 1);
  int* permA = (int*)carve(E);
  int* permN = (int*)carve(E);
  int* perm_new = (int*)carve(total_new);
  float* emb  = (float*)carve((size_t)N * F_FEAT);
  float* embn = (float*)carve((size_t)N * F_FEAT);
  float* Tm   = (float*)carve((size_t)N * F_FEAT);
  float* topv = (float*)carve(NK);
  int*   topi = (int*)carve(NK);
  float* pv = (float*)carve((size_t)N * nct * 5);
  int*   pi = (int*)carve((size_t)N * nct * 5);
  float* XW1  = (float*)carve((size_t)N * NHID);
  float* hbuf = (float*)carve((size_t)N * NHID);
  float* HW2  = (float*)carve((size_t)N * NCLASS);
  size_t planeBytes = (size_t)Npad * F_FEAT * 2;
  unsigned short* TA1 = (unsigned short*)carveB(planeBytes);
  unsigned short* TA2 = (unsigned short*)carveB(planeBytes);
  unsigned short* EB1 = (unsigned short*)carveB(planeBytes);
  unsigned short* EB2 = (unsigned short*)carveB(planeBytes);

  hipMemsetAsync(w + zstart, 0, zbytes, stream);

  int eb = (E + 255) / 256;
  k_deg_count<<<eb, 256, 0, stream>>>(ar, av, nr, nv, deg_adj, deg_ned, cntA, cntN, E);
  k_scan_pair<<<2, 1024, 0, stream>>>(cntA, rpA, cntN, rpN, N);
  k_rs<<<(N + 255) / 256, 256, 0, stream>>>(deg_adj, deg_ned, rs_adj, rinv_ned, N);
  k_fill2<<<eb, 256, 0, stream>>>(ar, nr, rpA, rpN, fillA, fillN, permA, permN, E);
  k_edgeval<<<eb, 256, 0, stream>>>(ar, ac, av, nr, nv, rs_adj, rinv_ned, adj_sym, ned_rw, E);
  k_spmm1<<<N, F_FEAT, 0, stream>>>(rpA, permA, ac, adj_sym, x, Wd1, emb, N);
  k_spmm2_norm<<<N, F_FEAT, 0, stream>>>(rpA, permA, ac, adj_sym, emb, Wd2, embn, N);
  k_spmmT<<<N, F_FEAT, 0, stream>>>(rpN, permN, nc, ned_rw, embn, Tm, N);
  int cvb = (Npad * (F_FEAT / 4) + 255) / 256;
  k_convert<<<cvb, 256, 0, stream>>>(Tm, TA1, TA2, N, Npad);
  k_convert<<<cvb, 256, 0, stream>>>(embn, EB1, EB2, N, Npad);
  k_gemm_topk<<<nrt * nct, 512, 0, stream>>>(TA1, TA2, EB1, EB2, pv, pi, N, nrt, nct);
  k_merge<<<(N + 255) / 256, 256, 0, stream>>>(pv, pi, topv, topi, deg_adj, deg_new, cntA, cnt_new, N, nct);
  k_scan_pair<<<1, 1024, 0, stream>>>(cnt_new, rp_new, nullptr, nullptr, N);
  k_rs_new<<<(N + 255) / 256, 256, 0, stream>>>(deg_new, rs_new, N);
  k_fill_new<<<(total_new + 255) / 256, 256, 0, stream>>>(ar, topi, rp_new, fill_new, perm_new, E, NK, total_new);
  k_xw1<<<(N + 7) / 8, 256, 0, stream>>>(x, W1, XW1, N);
  k_spmm_h<<<N, NHID, 0, stream>>>(rp_new, perm_new, ac, av, topi, topv, rs_new, XW1, b1, hbuf, N, E, NK);
  k_hw2<<<(N + 15) / 16, 256, 0, stream>>>(hbuf, W2, HW2, N);
  k_spmm_out<<<(N + 15) / 16, 256, 0, stream>>>(rp_new, perm_new, ac, av, topi, topv, rs_new, HW2, b2, (float*)d_out, N, E, NK);
}

// Round 7
// 1491.956 us; speedup vs baseline: 1.5445x; 1.0972x over previous
//
#include <hip/hip_runtime.h>
#include <cfloat>
#include <cstdint>

#define F_FEAT 256
#define NHID 128
#define NCLASS 16
#define KTOP 5
#define SCT 5            // col-tiles per strip
#define STRIPW (SCT * 256)

typedef _Float16 f16x8 __attribute__((ext_vector_type(8)));
typedef __attribute__((ext_vector_type(4))) float f32x4;

// ---------------- helpers ----------------
__device__ __forceinline__ void topk_insert5(float (&v)[5], int (&ix)[5], float cv, int ci) {
  // rank order: (value desc, index asc)  -- matches jax.lax.top_k
  if (cv < v[4] || (cv == v[4] && ci > ix[4])) return;
  int pos = 0;
#pragma unroll
  for (int j = 0; j < 5; ++j) pos += ((v[j] > cv) || (v[j] == cv && ix[j] < ci)) ? 1 : 0;
  if (pos >= 5) return;
  for (int j = 4; j > pos; --j) { v[j] = v[j - 1]; ix[j] = ix[j - 1]; }
  v[pos] = cv; ix[pos] = ci;
}

__device__ __forceinline__ void gload_lds16(const void* g, void* l) {
  __builtin_amdgcn_global_load_lds((const __attribute__((address_space(1))) void*)g,
                                   (__attribute__((address_space(3))) void*)l, 16, 0, 0);
}

// ---------------- graph prep ----------------
__global__ void k_deg_count(const int* __restrict__ ar, const float* __restrict__ av,
                            const int* __restrict__ nr, const float* __restrict__ nv,
                            float* deg_adj, float* deg_ned, int* cntA, int* cntN, int E) {
  int e = blockIdx.x * blockDim.x + threadIdx.x;
  if (e >= E) return;
  int ra = ar[e]; int rn = nr[e];
  atomicAdd(&deg_adj[ra], av[e]);
  atomicAdd(&deg_ned[rn], nv[e]);
  atomicAdd(&cntA[ra], 1);
  atomicAdd(&cntN[rn], 1);
}

__global__ __launch_bounds__(1024) void k_scan_pair(const int* c0, int* o0, const int* c1, int* o1, int n) {
  const int* c = (blockIdx.x == 0) ? c0 : c1;
  int* o = (blockIdx.x == 0) ? o0 : o1;
  if (c == nullptr) return;
  __shared__ int buf[1024];
  int tid = threadIdx.x;
  int base = 0;
  int chunks = (n + 1023) >> 10;
  for (int ch = 0; ch < chunks; ++ch) {
    int i = (ch << 10) + tid;
    buf[tid] = (i < n) ? c[i] : 0;
    __syncthreads();
    for (int offd = 1; offd < 1024; offd <<= 1) {
      int t = (tid >= offd) ? buf[tid - offd] : 0;
      __syncthreads();
      buf[tid] += t;
      __syncthreads();
    }
    if (i < n) o[i + 1] = base + buf[tid];
    int tot = buf[1023];
    __syncthreads();
    base += tot;
  }
  if (tid == 0) o[0] = 0;
}

__global__ void k_rs(const float* deg_adj, const float* deg_ned, float* rs_adj, float* rinv_ned, int N) {
  int i = blockIdx.x * blockDim.x + threadIdx.x;
  if (i >= N) return;
  rs_adj[i] = 1.0f / (sqrtf(deg_adj[i]) + 1e-10f);
  rinv_ned[i] = 1.0f / (deg_ned[i] + 1e-10f);
}

__global__ void k_fill2(const int* ar, const int* nr, const int* rpA, const int* rpN,
                        int* fillA, int* fillN, int* permA, int* permN, int E) {
  int e = blockIdx.x * blockDim.x + threadIdx.x;
  if (e >= E) return;
  int ra = ar[e];
  permA[rpA[ra] + atomicAdd(&fillA[ra], 1)] = e;
  int rn = nr[e];
  permN[rpN[rn] + atomicAdd(&fillN[rn], 1)] = e;
}

__global__ void k_edgeval(const int* ar, const int* ac, const float* av,
                          const int* nr, const float* nv,
                          const float* rs_adj, const float* rinv_ned,
                          float* adj_sym, float* ned_rw, int E) {
  int e = blockIdx.x * blockDim.x + threadIdx.x;
  if (e >= E) return;
  adj_sym[e] = av[e] * rs_adj[ar[e]] * rs_adj[ac[e]];
  ned_rw[e] = nv[e] * rinv_ned[nr[e]];
}

// ---------------- SpMMs (CSR, block per row, feature per thread) ----------------
__global__ void k_spmm1(const int* __restrict__ rpA, const int* __restrict__ permA,
                        const int* __restrict__ ac, const float* __restrict__ adj_sym,
                        const float* __restrict__ x, const float* __restrict__ Wd1,
                        float* __restrict__ emb, int N) {
  int r = blockIdx.x; int f = threadIdx.x;
  int s = rpA[r], e = rpA[r + 1];
  float acc = 0.f;
  for (int i = s; i < e; ++i) {
    int id = permA[i];
    acc += adj_sym[id] * x[(size_t)ac[id] * F_FEAT + f];
  }
  emb[(size_t)r * F_FEAT + f] = tanhf(acc * Wd1[f]);
}

__global__ void k_spmm2_norm(const int* __restrict__ rpA, const int* __restrict__ permA,
                             const int* __restrict__ ac, const float* __restrict__ adj_sym,
                             const float* __restrict__ emb, const float* __restrict__ Wd2,
                             float* __restrict__ embn, int N) {
  __shared__ float red[F_FEAT];
  int r = blockIdx.x; int f = threadIdx.x;
  int s = rpA[r], e = rpA[r + 1];
  float acc = 0.f;
  for (int i = s; i < e; ++i) {
    int id = permA[i];
    acc += adj_sym[id] * emb[(size_t)ac[id] * F_FEAT + f];
  }
  float val = acc * Wd2[f];
  red[f] = val * val;
  __syncthreads();
  for (int st = F_FEAT / 2; st > 0; st >>= 1) {
    if (f < st) red[f] += red[f + st];
    __syncthreads();
  }
  float rinv = 1.0f / (sqrtf(red[0]) + 1e-12f);
  embn[(size_t)r * F_FEAT + f] = val * rinv;
}

__global__ void k_spmmT(const int* __restrict__ rpN, const int* __restrict__ permN,
                        const int* __restrict__ nc, const float* __restrict__ ned_rw,
                        const float* __restrict__ embn, float* __restrict__ Tm, int N) {
  int r = blockIdx.x; int f = threadIdx.x;
  int s = rpN[r], e = rpN[r + 1];
  float acc = 0.f;
  for (int i = s; i < e; ++i) {
    int id = permN[i];
    acc += ned_rw[id] * embn[(size_t)nc[id] * F_FEAT + f];
  }
  Tm[(size_t)r * F_FEAT + f] = acc;
}

// ---- exact 2-way fp16 split: src[N][256] f32 -> 2 planes [Npad][256] fp16 ----
__global__ void k_convert(const float* __restrict__ src,
                          unsigned short* __restrict__ p1, unsigned short* __restrict__ p2,
                          int N, int Npad) {
  int idx = blockIdx.x * blockDim.x + threadIdx.x;   // one thread per 4 elems
  int total = Npad * (F_FEAT / 4);
  if (idx >= total) return;
  int row = idx >> 6;
  int c4 = (idx & 63) << 2;
  float4 v = make_float4(0.f, 0.f, 0.f, 0.f);
  if (row < N) v = *reinterpret_cast<const float4*>(src + (size_t)row * F_FEAT + c4);
  float arr[4] = {v.x, v.y, v.z, v.w};
  ushort4 o1, o2;
  unsigned short* q1 = (unsigned short*)&o1;
  unsigned short* q2 = (unsigned short*)&o2;
#pragma unroll
  for (int j = 0; j < 4; ++j) {
    float a = arr[j];
    _Float16 h1 = (_Float16)a;
    float r = a - (float)h1;      // exact
    _Float16 h2 = (_Float16)r;    // residual of residual <= 2^-22 |a|: dropped
    q1[j] = __builtin_bit_cast(unsigned short, h1);
    q2[j] = __builtin_bit_cast(unsigned short, h2);
  }
  size_t off = (size_t)row * F_FEAT + c4;
  *reinterpret_cast<ushort4*>(p1 + off) = o1;
  *reinterpret_cast<ushort4*>(p2 + off) = o2;
}

// ---- MFMA GEMM (T @ embn^T strip, f32-faithful via 3 fp16 products) -> C strip ----
// 256x256 tile, 8 waves, K=256 in 8 slabs of 32; double-buffered global_load_lds.
// Identical K-loop to R6 (verified); epilogue writes f32 C strip row-major [Npad][STRIPW].
__global__ __launch_bounds__(512, 1) void k_gemm_c(
    const unsigned short* __restrict__ A1, const unsigned short* __restrict__ A2,
    const unsigned short* __restrict__ B1, const unsigned short* __restrict__ B2,
    float* __restrict__ Cbuf, int ct0) {
  __shared__ __align__(16) unsigned short lds[2 * 4 * 256 * 32];   // 128 KB

  int tid = threadIdx.x;
  int lane = tid & 63;
  int wid = tid >> 6;        // 0..7
  int wr = wid >> 2;         // 0..1  row half (128 rows)
  int wc = wid & 3;          // 0..3  col quarter (64 cols)
  int lr = lane & 15;
  int lg = lane >> 4;

  int rt = blockIdx.x;
  int ctl = blockIdx.y;            // local col tile within strip
  int ct = ct0 + ctl;
  int row0 = rt * 256, col0 = ct * 256;

  // staging geometry: wave stages plane sp, half sh (128 rows = 8 x 1KB issues)
  int sp = wid >> 1, sh = wid & 1;
  const unsigned short* pg = (sp == 0) ? A1 : (sp == 1) ? A2 : (sp == 2) ? B1 : B2;
  int srow = lane >> 2;                         // 0..15
  int sslot = lane & 3;                         // linear 16B slot in LDS
  int sgslot = sslot ^ ((srow >> 1) & 3);       // pre-swizzled global slot
  int t0 = (sp < 2) ? row0 : col0;
  const char* gbase = (const char*)pg + ((size_t)(t0 + sh * 128 + srow) << 9) + sgslot * 16;
  char* lbase0 = (char*)lds + sp * 16384 + sh * 8192;   // wave-uniform

  int fslot = (lg ^ ((lr >> 1) & 3)) << 3;      // ushort offset of 16B unit (read side)

  f32x4 acc[8][4];
#pragma unroll
  for (int m = 0; m < 8; ++m)
#pragma unroll
    for (int n = 0; n < 4; ++n) acc[m][n] = (f32x4){0.f, 0.f, 0.f, 0.f};

  // prologue: stage slab 0 into buffer 0
#pragma unroll
  for (int i = 0; i < 8; ++i)
    gload_lds16(gbase + ((size_t)i << 13), lbase0 + (i << 10));
  __syncthreads();

  for (int ks = 0; ks < 8; ++ks) {
    int cur = ks & 1;
    if (ks < 7) {      // issue next slab into other buffer; latency hides under MFMA
      const char* g = gbase + (ks + 1) * 64;
      char* lb = lbase0 + ((cur ^ 1) << 16);
#pragma unroll
      for (int i = 0; i < 8; ++i)
        gload_lds16(g + ((size_t)i << 13), lb + (i << 10));
    }
    const unsigned short* bufp = lds + cur * 32768;   // ushort units
    f16x8 fb[2][4];
#pragma unroll
    for (int n = 0; n < 4; ++n) {
      int off = (wc * 64 + n * 16 + lr) * 32 + fslot;
      fb[0][n] = *reinterpret_cast<const f16x8*>(bufp + 2 * 8192 + off);
      fb[1][n] = *reinterpret_cast<const f16x8*>(bufp + 3 * 8192 + off);
    }
#pragma unroll
    for (int m = 0; m < 8; ++m) {
      int off = (wr * 128 + m * 16 + lr) * 32 + fslot;
      f16x8 fa1 = *reinterpret_cast<const f16x8*>(bufp + 0 * 8192 + off);
      f16x8 fa2 = *reinterpret_cast<const f16x8*>(bufp + 1 * 8192 + off);
#pragma unroll
      for (int n = 0; n < 4; ++n) {
        acc[m][n] = __builtin_amdgcn_mfma_f32_16x16x32_f16(fa1, fb[1][n], acc[m][n], 0, 0, 0);
        acc[m][n] = __builtin_amdgcn_mfma_f32_16x16x32_f16(fa2, fb[0][n], acc[m][n], 0, 0, 0);
        acc[m][n] = __builtin_amdgcn_mfma_f32_16x16x32_f16(fa1, fb[0][n], acc[m][n], 0, 0, 0);
      }
    }
    __syncthreads();   // reads of buf done (next iter overwrites) + staged loads drained
  }

  // ---- epilogue: store C strip (f32). 16-lane 64B segments per (m,n,rg).
#pragma unroll
  for (int m = 0; m < 8; ++m) {
#pragma unroll
    for (int rg = 0; rg < 4; ++rg) {
      int rl = wr * 128 + m * 16 + lg * 4 + rg;
      float* cr = Cbuf + (size_t)(row0 + rl) * STRIPW + ctl * 256 + wc * 64 + lr;
#pragma unroll
      for (int n = 0; n < 4; ++n) cr[n * 16] = acc[m][n][rg];
    }
  }
}

// ---- strip-wise per-row top-5: 64 lanes/row, butterfly merge, running state ----
__global__ __launch_bounds__(256) void k_topk(const float* __restrict__ Cbuf, int col0, int first,
                                              float* __restrict__ topv, int* __restrict__ topi, int N) {
  int wid = threadIdx.x >> 6, lane = threadIdx.x & 63;
  int r = blockIdx.x * 4 + wid;
  if (r >= N) return;
  float bv[5]; int bi[5];
#pragma unroll
  for (int k = 0; k < 5; ++k) { bv[k] = -FLT_MAX; bi[k] = 0x7fffffff; }
  const float* rowp = Cbuf + (size_t)r * STRIPW;
  for (int j = 0; j < STRIPW / 64; ++j) {
    int c = j * 64 + lane;
    int gc = col0 + c;
    float v = rowp[c];
    if (gc < N) topk_insert5(bv, bi, v, gc);
  }
#pragma unroll
  for (int d = 1; d < 64; d <<= 1) {
    float tv[5]; int ti[5];
#pragma unroll
    for (int k = 0; k < 5; ++k) { tv[k] = __shfl_xor(bv[k], d, 64); ti[k] = __shfl_xor(bi[k], d, 64); }
#pragma unroll
    for (int k = 0; k < 5; ++k) topk_insert5(bv, bi, tv[k], ti[k]);
  }
  if (lane == 0) {
    if (!first) {
#pragma unroll
      for (int k = 0; k < 5; ++k) topk_insert5(bv, bi, topv[(size_t)r * 5 + k], topi[(size_t)r * 5 + k]);
    }
#pragma unroll
    for (int k = 0; k < 5; ++k) { topv[(size_t)r * 5 + k] = bv[k]; topi[(size_t)r * 5 + k] = bi[k]; }
  }
}

// ---------------- degrees/counts from final top-5 ----------------
__global__ void k_merge(const float* __restrict__ topv, const int* __restrict__ topi,
                        const float* deg_adj, float* deg_new, const int* cntA, int* cnt_new, int N) {
  int r = blockIdx.x * blockDim.x + threadIdx.x;
  if (r >= N) return;
  float sumv = 0.f;
  for (int k = 0; k < 5; ++k) {
    float v = topv[(size_t)r * 5 + k];
    int ix = topi[(size_t)r * 5 + k];
    sumv += v;
    atomicAdd(&deg_new[ix], v);
    atomicAdd(&cnt_new[ix], 1);
  }
  atomicAdd(&deg_new[r], deg_adj[r] + sumv);
  atomicAdd(&cnt_new[r], cntA[r] + KTOP);
}

__global__ void k_rs_new(const float* deg_new, float* rs_new, int N) {
  int i = blockIdx.x * blockDim.x + threadIdx.x;
  if (i >= N) return;
  rs_new[i] = 1.0f / (sqrtf(deg_new[i]) + 1e-10f);
}

__global__ void k_fill_new(const int* ar, const int* topi, const int* rp_new, int* fill_new,
                           int* perm_new, int E, int NK, int total) {
  int t = blockIdx.x * blockDim.x + threadIdx.x;
  if (t >= total) return;
  int r;
  if (t < E) r = ar[t];
  else if (t < E + NK) r = (t - E) / KTOP;
  else r = topi[t - E - NK];
  perm_new[rp_new[r] + atomicAdd(&fill_new[r], 1)] = t;
}

// ---------------- dense layers ----------------
__global__ void k_xw1(const float* __restrict__ x, const float* __restrict__ W1,
                      float* __restrict__ XW1, int N) {
  int c = threadIdx.x & 127;
  int half = threadIdx.x >> 7;
  int r0 = blockIdx.x * 8 + half * 4;
  int rm = N - 1;
  const float* x0 = x + (size_t)min(r0 + 0, rm) * F_FEAT;
  const float* x1 = x + (size_t)min(r0 + 1, rm) * F_FEAT;
  const float* x2 = x + (size_t)min(r0 + 2, rm) * F_FEAT;
  const float* x3 = x + (size_t)min(r0 + 3, rm) * F_FEAT;
  float a0 = 0.f, a1 = 0.f, a2 = 0.f, a3 = 0.f;
  for (int k = 0; k < F_FEAT; ++k) {
    float wv = W1[k * NHID + c];
    a0 += x0[k] * wv; a1 += x1[k] * wv; a2 += x2[k] * wv; a3 += x3[k] * wv;
  }
  if (r0 + 0 < N) XW1[(size_t)(r0 + 0) * NHID + c] = a0;
  if (r0 + 1 < N) XW1[(size_t)(r0 + 1) * NHID + c] = a1;
  if (r0 + 2 < N) XW1[(size_t)(r0 + 2) * NHID + c] = a2;
  if (r0 + 3 < N) XW1[(size_t)(r0 + 3) * NHID + c] = a3;
}

__global__ void k_spmm_h(const int* __restrict__ rp, const int* __restrict__ perm,
                         const int* __restrict__ ac, const float* __restrict__ av,
                         const int* __restrict__ topi, const float* __restrict__ topv,
                         const float* __restrict__ rs, const float* __restrict__ XW1,
                         const float* __restrict__ b1, float* __restrict__ h,
                         int N, int E, int NK) {
  int r = blockIdx.x; int f = threadIdx.x;  // 128 threads
  int s = rp[r], e = rp[r + 1];
  float acc = 0.f;
  for (int i = s; i < e; ++i) {
    int id = perm[i];
    int c; float v;
    if (id < E) { c = ac[id]; v = av[id]; }
    else if (id < E + NK) { int q = id - E; c = topi[q]; v = topv[q]; }
    else { int q = id - E - NK; c = q / KTOP; v = topv[q]; }
    acc += v * rs[c] * XW1[(size_t)c * NHID + f];
  }
  float o = rs[r] * acc + b1[f];
  h[(size_t)r * NHID + f] = fmaxf(o, 0.f);
}

__global__ void k_hw2(const float* __restrict__ h, const float* __restrict__ W2,
                      float* __restrict__ HW2, int N) {
  int tid = threadIdx.x;
  int rr = tid >> 4, c = tid & 15;
  int r = blockIdx.x * 16 + rr;
  if (r >= N) return;
  float acc = 0.f;
  for (int k = 0; k < NHID; ++k) acc += h[(size_t)r * NHID + k] * W2[k * NCLASS + c];
  HW2[(size_t)r * NCLASS + c] = acc;
}

__global__ void k_spmm_out(const int* __restrict__ rp, const int* __restrict__ perm,
                           const int* __restrict__ ac, const float* __restrict__ av,
                           const int* __restrict__ topi, const float* __restrict__ topv,
                           const float* __restrict__ rs, const float* __restrict__ HW2,
                           const float* __restrict__ b2, float* __restrict__ out,
                           int N, int E, int NK) {
  int tid = threadIdx.x;
  int rr = tid >> 4, c = tid & 15;
  int r = blockIdx.x * 16 + rr;
  if (r >= N) return;
  int s = rp[r], e = rp[r + 1];
  float acc = 0.f;
  for (int i = s; i < e; ++i) {
    int id = perm[i];
    int cc; float v;
    if (id < E) { cc = ac[id]; v = av[id]; }
    else if (id < E + NK) { int q = id - E; cc = topi[q]; v = topv[q]; }
    else { int q = id - E - NK; cc = q / KTOP; v = topv[q]; }
    acc += v * rs[cc] * HW2[(size_t)cc * NCLASS + c];
  }
  out[(size_t)r * NCLASS + c] = rs[r] * acc + b2[c];
}

// ---------------- host ----------------
extern "C" void kernel_launch(void* const* d_in, const int* in_sizes, int n_in,
                              void* d_out, int out_size, void* d_ws, size_t ws_size,
                              hipStream_t stream) {
  (void)n_in; (void)out_size; (void)ws_size;
  const float* x   = (const float*)d_in[0];
  const int*   ar  = (const int*)d_in[1];
  const int*   ac  = (const int*)d_in[2];
  const float* av  = (const float*)d_in[3];
  const int*   nr  = (const int*)d_in[4];
  const int*   nc  = (const int*)d_in[5];
  const float* nv  = (const float*)d_in[6];
  const float* Wd1 = (const float*)d_in[7];
  const float* Wd2 = (const float*)d_in[8];
  const float* W1  = (const float*)d_in[9];
  const float* b1  = (const float*)d_in[10];
  const float* W2  = (const float*)d_in[11];
  const float* b2  = (const float*)d_in[12];
  int N = in_sizes[0] / F_FEAT;
  int E = in_sizes[3];
  int NK = N * KTOP;
  int total_new = E + 2 * NK;
  int Npad = ((N + 255) / 256) * 256;
  int nrt = Npad / 256;
  int nct = nrt;
  int nstrip = (nct + SCT - 1) / SCT;

  char* w = (char*)d_ws;
  size_t off = 0;
  auto carveB = [&](size_t bytes) -> void* {
    void* p = (void*)(w + off);
    off += (bytes + 255) & ~((size_t)255);
    return p;
  };
  auto carve = [&](size_t elems) -> void* { return carveB(elems * 4); };
  size_t zstart = off;
  float* deg_adj = (float*)carve(N);
  float* deg_ned = (float*)carve(N);
  float* deg_new = (float*)carve(N);
  int* cntA = (int*)carve(N);
  int* cntN = (int*)carve(N);
  int* cnt_new = (int*)carve(N);
  int* fillA = (int*)carve(N);
  int* fillN = (int*)carve(N);
  int* fill_new = (int*)carve(N);
  size_t zbytes = off - zstart;
  float* rs_adj = (float*)carve(N);
  float* rinv_ned = (float*)carve(N);
  float* rs_new = (float*)carve(N);
  float* adj_sym = (float*)carve(E);
  float* ned_rw = (float*)carve(E);
  int* rpA = (int*)carve(N + 1);
  int* rpN = (int*)carve(N + 1);
  int* rp_new = (int*)carve(N + 1);
  int* permA = (int*)carve(E);
  int* permN = (int*)carve(E);
  int* perm_new = (int*)carve(total_new);
  float* emb  = (float*)carve((size_t)N * F_FEAT);
  float* embn = (float*)carve((size_t)N * F_FEAT);
  float* Tm   = (float*)carve((size_t)N * F_FEAT);
  float* topv = (float*)carve(NK);
  int*   topi = (int*)carve(NK);
  float* XW1  = (float*)carve((size_t)N * NHID);
  float* hbuf = (float*)carve((size_t)N * NHID);
  float* HW2  = (float*)carve((size_t)N * NCLASS);
  size_t planeBytes = (size_t)Npad * F_FEAT * 2;
  unsigned short* TA1 = (unsigned short*)carveB(planeBytes);
  unsigned short* TA2 = (unsigned short*)carveB(planeBytes);
  unsigned short* EB1 = (unsigned short*)carveB(planeBytes);
  unsigned short* EB2 = (unsigned short*)carveB(planeBytes);
  float* Cbuf = (float*)carveB((size_t)Npad * STRIPW * 4);

  hipMemsetAsync(w + zstart, 0, zbytes, stream);

  int eb = (E + 255) / 256;
  k_deg_count<<<eb, 256, 0, stream>>>(ar, av, nr, nv, deg_adj, deg_ned, cntA, cntN, E);
  k_scan_pair<<<2, 1024, 0, stream>>>(cntA, rpA, cntN, rpN, N);
  k_rs<<<(N + 255) / 256, 256, 0, stream>>>(deg_adj, deg_ned, rs_adj, rinv_ned, N);
  k_fill2<<<eb, 256, 0, stream>>>(ar, nr, rpA, rpN, fillA, fillN, permA, permN, E);
  k_edgeval<<<eb, 256, 0, stream>>>(ar, ac, av, nr, nv, rs_adj, rinv_ned, adj_sym, ned_rw, E);
  k_spmm1<<<N, F_FEAT, 0, stream>>>(rpA, permA, ac, adj_sym, x, Wd1, emb, N);
  k_spmm2_norm<<<N, F_FEAT, 0, stream>>>(rpA, permA, ac, adj_sym, emb, Wd2, embn, N);
  k_spmmT<<<N, F_FEAT, 0, stream>>>(rpN, permN, nc, ned_rw, embn, Tm, N);
  int cvb = (Npad * (F_FEAT / 4) + 255) / 256;
  k_convert<<<cvb, 256, 0, stream>>>(Tm, TA1, TA2, N, Npad);
  k_convert<<<cvb, 256, 0, stream>>>(embn, EB1, EB2, N, Npad);

  for (int s = 0; s < nstrip; ++s) {
    dim3 gg(nrt, SCT);
    k_gemm_c<<<gg, 512, 0, stream>>>(TA1, TA2, EB1, EB2, Cbuf, s * SCT);
    k_topk<<<(N + 3) / 4, 256, 0, stream>>>(Cbuf, s * STRIPW, (s == 0) ? 1 : 0, topv, topi, N);
  }

  k_merge<<<(N + 255) / 256, 256, 0, stream>>>(topv, topi, deg_adj, deg_new, cntA, cnt_new, N);
  k_scan_pair<<<1, 1024, 0, stream>>>(cnt_new, rp_new, nullptr, nullptr, N);
  k_rs_new<<<(N + 255) / 256, 256, 0, stream>>>(deg_new, rs_new, N);
  k_fill_new<<<(total_new + 255) / 256, 256, 0, stream>>>(ar, topi, rp_new, fill_new, perm_new, E, NK, total_new);
  k_xw1<<<(N + 7) / 8, 256, 0, stream>>>(x, W1, XW1, N);
  k_spmm_h<<<N, NHID, 0, stream>>>(rp_new, perm_new, ac, av, topi, topv, rs_new, XW1, b1, hbuf, N, E, NK);
  k_hw2<<<(N + 15) / 16, 256, 0, stream>>>(hbuf, W2, HW2, N);
  k_spmm_out<<<(N + 15) / 16, 256, 0, stream>>>(rp_new, perm_new, ac, av, topi, topv, rs_new, HW2, b2, (float*)d_out, N, E, NK);
}

// Round 8
// 938.940 us; speedup vs baseline: 2.4542x; 1.5890x over previous
//
#include <hip/hip_runtime.h>
#include <cfloat>
#include <cstdint>

#define F_FEAT 256
#define NHID 128
#define NCLASS 16
#define KTOP 5
#define SCT 5            // col-tiles per strip
#define STRIPW (SCT * 256)

typedef _Float16 f16x8 __attribute__((ext_vector_type(8)));
typedef __attribute__((ext_vector_type(4))) float f32x4;
typedef unsigned long long u64;

// ---------------- helpers ----------------
__device__ __forceinline__ void topk_insert5(float (&v)[5], int (&ix)[5], float cv, int ci) {
  if (cv < v[4] || (cv == v[4] && ci > ix[4])) return;
  int pos = 0;
#pragma unroll
  for (int j = 0; j < 5; ++j) pos += ((v[j] > cv) || (v[j] == cv && ix[j] < ci)) ? 1 : 0;
  if (pos >= 5) return;
  for (int j = 4; j > pos; --j) { v[j] = v[j - 1]; ix[j] = ix[j - 1]; }
  v[pos] = cv; ix[pos] = ci;
}

__device__ __forceinline__ void gload_lds16(const void* g, void* l) {
  __builtin_amdgcn_global_load_lds((const __attribute__((address_space(1))) void*)g,
                                   (__attribute__((address_space(3))) void*)l, 16, 0, 0);
}

// packed (value desc, index asc) total-order key: bigger key = better candidate
__device__ __forceinline__ u64 packkey(float v, int idx) {
  unsigned u = __float_as_uint(v);
  u ^= (u >> 31) ? 0xFFFFFFFFu : 0x80000000u;       // monotone f32 -> u32
  return ((u64)u << 32) | (unsigned)(0x7FFFFFFF - idx);
}
__device__ __forceinline__ void unpackkey(u64 key, float& v, int& idx) {
  unsigned u = (unsigned)(key >> 32);
  u ^= (u >> 31) ? 0x80000000u : 0xFFFFFFFFu;
  v = __uint_as_float(u);
  idx = 0x7FFFFFFF - (int)(key & 0xFFFFFFFFu);
}
__device__ __forceinline__ u64 umax64(u64 a, u64 b) { return a > b ? a : b; }
__device__ __forceinline__ u64 umin64(u64 a, u64 b) { return a > b ? b : a; }

// branchless insert of k into sorted-desc {s0..s4}
__device__ __forceinline__ void ins5(u64& s0, u64& s1, u64& s2, u64& s3, u64& s4, u64 k) {
  u64 t;
  t = umin64(s0, k); s0 = umax64(s0, k); k = t;
  t = umin64(s1, k); s1 = umax64(s1, k); k = t;
  t = umin64(s2, k); s2 = umax64(s2, k); k = t;
  t = umin64(s3, k); s3 = umax64(s3, k); k = t;
  s4 = umax64(s4, k);
}

// top-5 of two sorted-desc 5-lists (merge-path network: 10 min, 15 max)
__device__ __forceinline__ void merge5(u64& a0, u64& a1, u64& a2, u64& a3, u64& a4,
                                       u64 b0, u64 b1, u64 b2, u64 b3, u64 b4) {
  u64 x00 = umin64(a0, b0);
  u64 x01 = umin64(a0, b1), x10 = umin64(a1, b0);
  u64 x02 = umin64(a0, b2), x11 = umin64(a1, b1), x20 = umin64(a2, b0);
  u64 x03 = umin64(a0, b3), x12 = umin64(a1, b2), x21 = umin64(a2, b1), x30 = umin64(a3, b0);
  u64 c0 = umax64(a0, b0);
  u64 c1 = umax64(x00, umax64(a1, b1));
  u64 c2 = umax64(umax64(x01, x10), umax64(a2, b2));
  u64 c3 = umax64(umax64(x02, x20), umax64(x11, umax64(a3, b3)));
  u64 c4 = umax64(umax64(umax64(x03, x30), umax64(x12, x21)), umax64(a4, b4));
  a0 = c0; a1 = c1; a2 = c2; a3 = c3; a4 = c4;
}

__device__ __forceinline__ u64 shflx64(u64 v, int m) {
  int lo = __shfl_xor((int)(unsigned)(v & 0xFFFFFFFFull), m, 64);
  int hi = __shfl_xor((int)(unsigned)(v >> 32), m, 64);
  return ((u64)(unsigned)hi << 32) | (unsigned)lo;
}

// ---------------- graph prep ----------------
__global__ void k_deg_count(const int* __restrict__ ar, const float* __restrict__ av,
                            const int* __restrict__ nr, const float* __restrict__ nv,
                            float* deg_adj, float* deg_ned, int* cntA, int* cntN, int E) {
  int e = blockIdx.x * blockDim.x + threadIdx.x;
  if (e >= E) return;
  int ra = ar[e]; int rn = nr[e];
  atomicAdd(&deg_adj[ra], av[e]);
  atomicAdd(&deg_ned[rn], nv[e]);
  atomicAdd(&cntA[ra], 1);
  atomicAdd(&cntN[rn], 1);
}

__global__ __launch_bounds__(1024) void k_scan_pair(const int* c0, int* o0, const int* c1, int* o1, int n) {
  const int* c = (blockIdx.x == 0) ? c0 : c1;
  int* o = (blockIdx.x == 0) ? o0 : o1;
  if (c == nullptr) return;
  __shared__ int buf[1024];
  int tid = threadIdx.x;
  int base = 0;
  int chunks = (n + 1023) >> 10;
  for (int ch = 0; ch < chunks; ++ch) {
    int i = (ch << 10) + tid;
    buf[tid] = (i < n) ? c[i] : 0;
    __syncthreads();
    for (int offd = 1; offd < 1024; offd <<= 1) {
      int t = (tid >= offd) ? buf[tid - offd] : 0;
      __syncthreads();
      buf[tid] += t;
      __syncthreads();
    }
    if (i < n) o[i + 1] = base + buf[tid];
    int tot = buf[1023];
    __syncthreads();
    base += tot;
  }
  if (tid == 0) o[0] = 0;
}

__global__ void k_rs(const float* deg_adj, const float* deg_ned, float* rs_adj, float* rinv_ned, int N) {
  int i = blockIdx.x * blockDim.x + threadIdx.x;
  if (i >= N) return;
  rs_adj[i] = 1.0f / (sqrtf(deg_adj[i]) + 1e-10f);
  rinv_ned[i] = 1.0f / (deg_ned[i] + 1e-10f);
}

__global__ void k_fill2(const int* ar, const int* nr, const int* rpA, const int* rpN,
                        int* fillA, int* fillN, int* permA, int* permN, int E) {
  int e = blockIdx.x * blockDim.x + threadIdx.x;
  if (e >= E) return;
  int ra = ar[e];
  permA[rpA[ra] + atomicAdd(&fillA[ra], 1)] = e;
  int rn = nr[e];
  permN[rpN[rn] + atomicAdd(&fillN[rn], 1)] = e;
}

__global__ void k_edgeval(const int* ar, const int* ac, const float* av,
                          const int* nr, const float* nv,
                          const float* rs_adj, const float* rinv_ned,
                          float* adj_sym, float* ned_rw, int E) {
  int e = blockIdx.x * blockDim.x + threadIdx.x;
  if (e >= E) return;
  adj_sym[e] = av[e] * rs_adj[ar[e]] * rs_adj[ac[e]];
  ned_rw[e] = nv[e] * rinv_ned[nr[e]];
}

// ---------------- SpMMs (CSR, block per row, feature per thread) ----------------
__global__ void k_spmm1(const int* __restrict__ rpA, const int* __restrict__ permA,
                        const int* __restrict__ ac, const float* __restrict__ adj_sym,
                        const float* __restrict__ x, const float* __restrict__ Wd1,
                        float* __restrict__ emb, int N) {
  int r = blockIdx.x; int f = threadIdx.x;
  int s = rpA[r], e = rpA[r + 1];
  float acc = 0.f;
  for (int i = s; i < e; ++i) {
    int id = permA[i];
    acc += adj_sym[id] * x[(size_t)ac[id] * F_FEAT + f];
  }
  emb[(size_t)r * F_FEAT + f] = tanhf(acc * Wd1[f]);
}

__global__ void k_spmm2_norm(const int* __restrict__ rpA, const int* __restrict__ permA,
                             const int* __restrict__ ac, const float* __restrict__ adj_sym,
                             const float* __restrict__ emb, const float* __restrict__ Wd2,
                             float* __restrict__ embn, int N) {
  __shared__ float red[F_FEAT];
  int r = blockIdx.x; int f = threadIdx.x;
  int s = rpA[r], e = rpA[r + 1];
  float acc = 0.f;
  for (int i = s; i < e; ++i) {
    int id = permA[i];
    acc += adj_sym[id] * emb[(size_t)ac[id] * F_FEAT + f];
  }
  float val = acc * Wd2[f];
  red[f] = val * val;
  __syncthreads();
  for (int st = F_FEAT / 2; st > 0; st >>= 1) {
    if (f < st) red[f] += red[f + st];
    __syncthreads();
  }
  float rinv = 1.0f / (sqrtf(red[0]) + 1e-12f);
  embn[(size_t)r * F_FEAT + f] = val * rinv;
}

__global__ void k_spmmT(const int* __restrict__ rpN, const int* __restrict__ permN,
                        const int* __restrict__ nc, const float* __restrict__ ned_rw,
                        const float* __restrict__ embn, float* __restrict__ Tm, int N) {
  int r = blockIdx.x; int f = threadIdx.x;
  int s = rpN[r], e = rpN[r + 1];
  float acc = 0.f;
  for (int i = s; i < e; ++i) {
    int id = permN[i];
    acc += ned_rw[id] * embn[(size_t)nc[id] * F_FEAT + f];
  }
  Tm[(size_t)r * F_FEAT + f] = acc;
}

// ---- exact 2-way fp16 split: src[N][256] f32 -> 2 planes [Npad][256] fp16 ----
__global__ void k_convert(const float* __restrict__ src,
                          unsigned short* __restrict__ p1, unsigned short* __restrict__ p2,
                          int N, int Npad) {
  int idx = blockIdx.x * blockDim.x + threadIdx.x;   // one thread per 4 elems
  int total = Npad * (F_FEAT / 4);
  if (idx >= total) return;
  int row = idx >> 6;
  int c4 = (idx & 63) << 2;
  float4 v = make_float4(0.f, 0.f, 0.f, 0.f);
  if (row < N) v = *reinterpret_cast<const float4*>(src + (size_t)row * F_FEAT + c4);
  float arr[4] = {v.x, v.y, v.z, v.w};
  ushort4 o1, o2;
  unsigned short* q1 = (unsigned short*)&o1;
  unsigned short* q2 = (unsigned short*)&o2;
#pragma unroll
  for (int j = 0; j < 4; ++j) {
    float a = arr[j];
    _Float16 h1 = (_Float16)a;
    float r = a - (float)h1;      // exact
    _Float16 h2 = (_Float16)r;
    q1[j] = __builtin_bit_cast(unsigned short, h1);
    q2[j] = __builtin_bit_cast(unsigned short, h2);
  }
  size_t off = (size_t)row * F_FEAT + c4;
  *reinterpret_cast<ushort4*>(p1 + off) = o1;
  *reinterpret_cast<ushort4*>(p2 + off) = o2;
}

// ---- MFMA GEMM (T @ embn^T strip, f32-faithful via 3 fp16 products) -> C strip ----
__global__ __launch_bounds__(512, 1) void k_gemm_c(
    const unsigned short* __restrict__ A1, const unsigned short* __restrict__ A2,
    const unsigned short* __restrict__ B1, const unsigned short* __restrict__ B2,
    float* __restrict__ Cbuf, int ct0) {
  __shared__ __align__(16) unsigned short lds[2 * 4 * 256 * 32];   // 128 KB

  int tid = threadIdx.x;
  int lane = tid & 63;
  int wid = tid >> 6;        // 0..7
  int wr = wid >> 2;         // 0..1  row half (128 rows)
  int wc = wid & 3;          // 0..3  col quarter (64 cols)
  int lr = lane & 15;
  int lg = lane >> 4;

  int rt = blockIdx.x;
  int ctl = blockIdx.y;            // local col tile within strip
  int ct = ct0 + ctl;
  int row0 = rt * 256, col0 = ct * 256;

  int sp = wid >> 1, sh = wid & 1;
  const unsigned short* pg = (sp == 0) ? A1 : (sp == 1) ? A2 : (sp == 2) ? B1 : B2;
  int srow = lane >> 2;
  int sslot = lane & 3;
  int sgslot = sslot ^ ((srow >> 1) & 3);
  int t0 = (sp < 2) ? row0 : col0;
  const char* gbase = (const char*)pg + ((size_t)(t0 + sh * 128 + srow) << 9) + sgslot * 16;
  char* lbase0 = (char*)lds + sp * 16384 + sh * 8192;

  int fslot = (lg ^ ((lr >> 1) & 3)) << 3;

  f32x4 acc[8][4];
#pragma unroll
  for (int m = 0; m < 8; ++m)
#pragma unroll
    for (int n = 0; n < 4; ++n) acc[m][n] = (f32x4){0.f, 0.f, 0.f, 0.f};

#pragma unroll
  for (int i = 0; i < 8; ++i)
    gload_lds16(gbase + ((size_t)i << 13), lbase0 + (i << 10));
  __syncthreads();

  for (int ks = 0; ks < 8; ++ks) {
    int cur = ks & 1;
    if (ks < 7) {
      const char* g = gbase + (ks + 1) * 64;
      char* lb = lbase0 + ((cur ^ 1) << 16);
#pragma unroll
      for (int i = 0; i < 8; ++i)
        gload_lds16(g + ((size_t)i << 13), lb + (i << 10));
    }
    const unsigned short* bufp = lds + cur * 32768;
    f16x8 fb[2][4];
#pragma unroll
    for (int n = 0; n < 4; ++n) {
      int off = (wc * 64 + n * 16 + lr) * 32 + fslot;
      fb[0][n] = *reinterpret_cast<const f16x8*>(bufp + 2 * 8192 + off);
      fb[1][n] = *reinterpret_cast<const f16x8*>(bufp + 3 * 8192 + off);
    }
#pragma unroll
    for (int m = 0; m < 8; ++m) {
      int off = (wr * 128 + m * 16 + lr) * 32 + fslot;
      f16x8 fa1 = *reinterpret_cast<const f16x8*>(bufp + 0 * 8192 + off);
      f16x8 fa2 = *reinterpret_cast<const f16x8*>(bufp + 1 * 8192 + off);
#pragma unroll
      for (int n = 0; n < 4; ++n) {
        acc[m][n] = __builtin_amdgcn_mfma_f32_16x16x32_f16(fa1, fb[1][n], acc[m][n], 0, 0, 0);
        acc[m][n] = __builtin_amdgcn_mfma_f32_16x16x32_f16(fa2, fb[0][n], acc[m][n], 0, 0, 0);
        acc[m][n] = __builtin_amdgcn_mfma_f32_16x16x32_f16(fa1, fb[0][n], acc[m][n], 0, 0, 0);
      }
    }
    __syncthreads();
  }

#pragma unroll
  for (int m = 0; m < 8; ++m) {
#pragma unroll
    for (int rg = 0; rg < 4; ++rg) {
      int rl = wr * 128 + m * 16 + lg * 4 + rg;
      float* cr = Cbuf + (size_t)(row0 + rl) * STRIPW + ctl * 256 + wc * 64 + lr;
#pragma unroll
      for (int n = 0; n < 4; ++n) cr[n * 16] = acc[m][n][rg];
    }
  }
}

// ---- strip-wise per-row top-5: branchless u64-key scan + merge-path butterfly ----
__global__ __launch_bounds__(256) void k_topk(const float* __restrict__ Cbuf, int col0, int first,
                                              u64* __restrict__ Kst, int N) {
  int wid = threadIdx.x >> 6, lane = threadIdx.x & 63;
  int r = blockIdx.x * 4 + wid;
  if (r >= N) return;
  const float4* rowp = reinterpret_cast<const float4*>(Cbuf + (size_t)r * STRIPW);
  float4 vv[SCT];
#pragma unroll
  for (int j = 0; j < SCT; ++j) vv[j] = rowp[j * 64 + lane];   // independent, issued early

  u64 s0 = 0, s1 = 0, s2 = 0, s3 = 0, s4 = 0;
#pragma unroll
  for (int j = 0; j < SCT; ++j) {
    int cb = col0 + (j * 64 + lane) * 4;
    float arr[4] = {vv[j].x, vv[j].y, vv[j].z, vv[j].w};
#pragma unroll
    for (int q = 0; q < 4; ++q) {
      int gc = cb + q;
      u64 key = (gc < N) ? packkey(arr[q], gc) : 0ull;
      ins5(s0, s1, s2, s3, s4, key);
    }
  }
#pragma unroll
  for (int d = 1; d < 64; d <<= 1) {
    u64 t0 = shflx64(s0, d), t1 = shflx64(s1, d), t2 = shflx64(s2, d),
        t3 = shflx64(s3, d), t4 = shflx64(s4, d);
    merge5(s0, s1, s2, s3, s4, t0, t1, t2, t3, t4);
  }
  if (lane == 0) {
    u64* st = Kst + (size_t)r * 5;
    if (!first) merge5(s0, s1, s2, s3, s4, st[0], st[1], st[2], st[3], st[4]);
    st[0] = s0; st[1] = s1; st[2] = s2; st[3] = s3; st[4] = s4;
  }
}

// ---------------- unpack + degrees/counts from final top-5 ----------------
__global__ void k_merge(const u64* __restrict__ Kst,
                        float* __restrict__ topv, int* __restrict__ topi,
                        const float* deg_adj, float* deg_new, const int* cntA, int* cnt_new, int N) {
  int r = blockIdx.x * blockDim.x + threadIdx.x;
  if (r >= N) return;
  float sumv = 0.f;
  for (int k = 0; k < 5; ++k) {
    float v; int ix;
    unpackkey(Kst[(size_t)r * 5 + k], v, ix);
    topv[(size_t)r * 5 + k] = v;
    topi[(size_t)r * 5 + k] = ix;
    sumv += v;
    atomicAdd(&deg_new[ix], v);
    atomicAdd(&cnt_new[ix], 1);
  }
  atomicAdd(&deg_new[r], deg_adj[r] + sumv);
  atomicAdd(&cnt_new[r], cntA[r] + KTOP);
}

__global__ void k_rs_new(const float* deg_new, float* rs_new, int N) {
  int i = blockIdx.x * blockDim.x + threadIdx.x;
  if (i >= N) return;
  rs_new[i] = 1.0f / (sqrtf(deg_new[i]) + 1e-10f);
}

__global__ void k_fill_new(const int* ar, const int* topi, const int* rp_new, int* fill_new,
                           int* perm_new, int E, int NK, int total) {
  int t = blockIdx.x * blockDim.x + threadIdx.x;
  if (t >= total) return;
  int r;
  if (t < E) r = ar[t];
  else if (t < E + NK) r = (t - E) / KTOP;
  else r = topi[t - E - NK];
  perm_new[rp_new[r] + atomicAdd(&fill_new[r], 1)] = t;
}

// ---------------- dense layers ----------------
__global__ void k_xw1(const float* __restrict__ x, const float* __restrict__ W1,
                      float* __restrict__ XW1, int N) {
  int c = threadIdx.x & 127;
  int half = threadIdx.x >> 7;
  int r0 = blockIdx.x * 8 + half * 4;
  int rm = N - 1;
  const float* x0 = x + (size_t)min(r0 + 0, rm) * F_FEAT;
  const float* x1 = x + (size_t)min(r0 + 1, rm) * F_FEAT;
  const float* x2 = x + (size_t)min(r0 + 2, rm) * F_FEAT;
  const float* x3 = x + (size_t)min(r0 + 3, rm) * F_FEAT;
  float a0 = 0.f, a1 = 0.f, a2 = 0.f, a3 = 0.f;
  for (int k = 0; k < F_FEAT; ++k) {
    float wv = W1[k * NHID + c];
    a0 += x0[k] * wv; a1 += x1[k] * wv; a2 += x2[k] * wv; a3 += x3[k] * wv;
  }
  if (r0 + 0 < N) XW1[(size_t)(r0 + 0) * NHID + c] = a0;
  if (r0 + 1 < N) XW1[(size_t)(r0 + 1) * NHID + c] = a1;
  if (r0 + 2 < N) XW1[(size_t)(r0 + 2) * NHID + c] = a2;
  if (r0 + 3 < N) XW1[(size_t)(r0 + 3) * NHID + c] = a3;
}

__global__ void k_spmm_h(const int* __restrict__ rp, const int* __restrict__ perm,
                         const int* __restrict__ ac, const float* __restrict__ av,
                         const int* __restrict__ topi, const float* __restrict__ topv,
                         const float* __restrict__ rs, const float* __restrict__ XW1,
                         const float* __restrict__ b1, float* __restrict__ h,
                         int N, int E, int NK) {
  int r = blockIdx.x; int f = threadIdx.x;  // 128 threads
  int s = rp[r], e = rp[r + 1];
  float acc = 0.f;
  for (int i = s; i < e; ++i) {
    int id = perm[i];
    int c; float v;
    if (id < E) { c = ac[id]; v = av[id]; }
    else if (id < E + NK) { int q = id - E; c = topi[q]; v = topv[q]; }
    else { int q = id - E - NK; c = q / KTOP; v = topv[q]; }
    acc += v * rs[c] * XW1[(size_t)c * NHID + f];
  }
  float o = rs[r] * acc + b1[f];
  h[(size_t)r * NHID + f] = fmaxf(o, 0.f);
}

__global__ void k_hw2(const float* __restrict__ h, const float* __restrict__ W2,
                      float* __restrict__ HW2, int N) {
  int tid = threadIdx.x;
  int rr = tid >> 4, c = tid & 15;
  int r = blockIdx.x * 16 + rr;
  if (r >= N) return;
  float acc = 0.f;
  for (int k = 0; k < NHID; ++k) acc += h[(size_t)r * NHID + k] * W2[k * NCLASS + c];
  HW2[(size_t)r * NCLASS + c] = acc;
}

__global__ void k_spmm_out(const int* __restrict__ rp, const int* __restrict__ perm,
                           const int* __restrict__ ac, const float* __restrict__ av,
                           const int* __restrict__ topi, const float* __restrict__ topv,
                           const float* __restrict__ rs, const float* __restrict__ HW2,
                           const float* __restrict__ b2, float* __restrict__ out,
                           int N, int E, int NK) {
  int tid = threadIdx.x;
  int rr = tid >> 4, c = tid & 15;
  int r = blockIdx.x * 16 + rr;
  if (r >= N) return;
  int s = rp[r], e = rp[r + 1];
  float acc = 0.f;
  for (int i = s; i < e; ++i) {
    int id = perm[i];
    int cc; float v;
    if (id < E) { cc = ac[id]; v = av[id]; }
    else if (id < E + NK) { int q = id - E; cc = topi[q]; v = topv[q]; }
    else { int q = id - E - NK; cc = q / KTOP; v = topv[q]; }
    acc += v * rs[cc] * HW2[(size_t)cc * NCLASS + c];
  }
  out[(size_t)r * NCLASS + c] = rs[r] * acc + b2[c];
}

// ---------------- host ----------------
extern "C" void kernel_launch(void* const* d_in, const int* in_sizes, int n_in,
                              void* d_out, int out_size, void* d_ws, size_t ws_size,
                              hipStream_t stream) {
  (void)n_in; (void)out_size; (void)ws_size;
  const float* x   = (const float*)d_in[0];
  const int*   ar  = (const int*)d_in[1];
  const int*   ac  = (const int*)d_in[2];
  const float* av  = (const float*)d_in[3];
  const int*   nr  = (const int*)d_in[4];
  const int*   nc  = (const int*)d_in[5];
  const float* nv  = (const float*)d_in[6];
  const float* Wd1 = (const float*)d_in[7];
  const float* Wd2 = (const float*)d_in[8];
  const float* W1  = (const float*)d_in[9];
  const float* b1  = (const float*)d_in[10];
  const float* W2  = (const float*)d_in[11];
  const float* b2  = (const float*)d_in[12];
  int N = in_sizes[0] / F_FEAT;
  int E = in_sizes[3];
  int NK = N * KTOP;
  int total_new = E + 2 * NK;
  int Npad = ((N + 255) / 256) * 256;
  int nrt = Npad / 256;
  int nct = nrt;
  int nstrip = (nct + SCT - 1) / SCT;

  char* w = (char*)d_ws;
  size_t off = 0;
  auto carveB = [&](size_t bytes) -> void* {
    void* p = (void*)(w + off);
    off += (bytes + 255) & ~((size_t)255);
    return p;
  };
  auto carve = [&](size_t elems) -> void* { return carveB(elems * 4); };
  size_t zstart = off;
  float* deg_adj = (float*)carve(N);
  float* deg_ned = (float*)carve(N);
  float* deg_new = (float*)carve(N);
  int* cntA = (int*)carve(N);
  int* cntN = (int*)carve(N);
  int* cnt_new = (int*)carve(N);
  int* fillA = (int*)carve(N);
  int* fillN = (int*)carve(N);
  int* fill_new = (int*)carve(N);
  size_t zbytes = off - zstart;
  float* rs_adj = (float*)carve(N);
  float* rinv_ned = (float*)carve(N);
  float* rs_new = (float*)carve(N);
  float* adj_sym = (float*)carve(E);
  float* ned_rw = (float*)carve(E);
  int* rpA = (int*)carve(N + 1);
  int* rpN = (int*)carve(N + 1);
  int* rp_new = (int*)carve(N + 1);
  int* permA = (int*)carve(E);
  int* permN = (int*)carve(E);
  int* perm_new = (int*)carve(total_new);
  float* emb  = (float*)carve((size_t)N * F_FEAT);
  float* embn = (float*)carve((size_t)N * F_FEAT);
  float* Tm   = (float*)carve((size_t)N * F_FEAT);
  float* topv = (float*)carve(NK);
  int*   topi = (int*)carve(NK);
  u64*   Kst  = (u64*)carveB((size_t)NK * 8);
  float* XW1  = (float*)carve((size_t)N * NHID);
  float* hbuf = (float*)carve((size_t)N * NHID);
  float* HW2  = (float*)carve((size_t)N * NCLASS);
  size_t planeBytes = (size_t)Npad * F_FEAT * 2;
  unsigned short* TA1 = (unsigned short*)carveB(planeBytes);
  unsigned short* TA2 = (unsigned short*)carveB(planeBytes);
  unsigned short* EB1 = (unsigned short*)carveB(planeBytes);
  unsigned short* EB2 = (unsigned short*)carveB(planeBytes);
  float* Cbuf = (float*)carveB((size_t)Npad * STRIPW * 4);

  hipMemsetAsync(w + zstart, 0, zbytes, stream);

  int eb = (E + 255) / 256;
  k_deg_count<<<eb, 256, 0, stream>>>(ar, av, nr, nv, deg_adj, deg_ned, cntA, cntN, E);
  k_scan_pair<<<2, 1024, 0, stream>>>(cntA, rpA, cntN, rpN, N);
  k_rs<<<(N + 255) / 256, 256, 0, stream>>>(deg_adj, deg_ned, rs_adj, rinv_ned, N);
  k_fill2<<<eb, 256, 0, stream>>>(ar, nr, rpA, rpN, fillA, fillN, permA, permN, E);
  k_edgeval<<<eb, 256, 0, stream>>>(ar, ac, av, nr, nv, rs_adj, rinv_ned, adj_sym, ned_rw, E);
  k_spmm1<<<N, F_FEAT, 0, stream>>>(rpA, permA, ac, adj_sym, x, Wd1, emb, N);
  k_spmm2_norm<<<N, F_FEAT, 0, stream>>>(rpA, permA, ac, adj_sym, emb, Wd2, embn, N);
  k_spmmT<<<N, F_FEAT, 0, stream>>>(rpN, permN, nc, ned_rw, embn, Tm, N);
  int cvb = (Npad * (F_FEAT / 4) + 255) / 256;
  k_convert<<<cvb, 256, 0, stream>>>(Tm, TA1, TA2, N, Npad);
  k_convert<<<cvb, 256, 0, stream>>>(embn, EB1, EB2, N, Npad);

  for (int s = 0; s < nstrip; ++s) {
    dim3 gg(nrt, SCT);
    k_gemm_c<<<gg, 512, 0, stream>>>(TA1, TA2, EB1, EB2, Cbuf, s * SCT);
    k_topk<<<(N + 3) / 4, 256, 0, stream>>>(Cbuf, s * STRIPW, (s == 0) ? 1 : 0, Kst, N);
  }

  k_merge<<<(N + 255) / 256, 256, 0, stream>>>(Kst, topv, topi, deg_adj, deg_new, cntA, cnt_new, N);
  k_scan_pair<<<1, 1024, 0, stream>>>(cnt_new, rp_new, nullptr, nullptr, N);
  k_rs_new<<<(N + 255) / 256, 256, 0, stream>>>(deg_new, rs_new, N);
  k_fill_new<<<(total_new + 255) / 256, 256, 0, stream>>>(ar, topi, rp_new, fill_new, perm_new, E, NK, total_new);
  k_xw1<<<(N + 7) / 8, 256, 0, stream>>>(x, W1, XW1, N);
  k_spmm_h<<<N, NHID, 0, stream>>>(rp_new, perm_new, ac, av, topi, topv, rs_new, XW1, b1, hbuf, N, E, NK);
  k_hw2<<<(N + 15) / 16, 256, 0, stream>>>(hbuf, W2, HW2, N);
  k_spmm_out<<<(N + 15) / 16, 256, 0, stream>>>(rp_new, perm_new, ac, av, topi, topv, rs_new, HW2, b2, (float*)d_out, N, E, NK);
}

// Round 9
// 808.045 us; speedup vs baseline: 2.8518x; 1.1620x over previous
//
#include <hip/hip_runtime.h>
#include <cfloat>
#include <cstdint>

#define F_FEAT 256
#define NHID 128
#define NCLASS 16
#define KTOP 5
#define SCT 5            // col-tiles per strip
#define STRIPW (SCT * 256)

typedef _Float16 f16x8 __attribute__((ext_vector_type(8)));
typedef __attribute__((ext_vector_type(4))) float f32x4;
typedef unsigned long long u64;

// ---------------- helpers ----------------
__device__ __forceinline__ void gload_lds16(const void* g, void* l) {
  __builtin_amdgcn_global_load_lds((const __attribute__((address_space(1))) void*)g,
                                   (__attribute__((address_space(3))) void*)l, 16, 0, 0);
}

// packed (value desc, index asc) total-order key: bigger key = better candidate
__device__ __forceinline__ u64 packkey(float v, int idx) {
  unsigned u = __float_as_uint(v);
  u ^= (u >> 31) ? 0xFFFFFFFFu : 0x80000000u;       // monotone f32 -> u32
  return ((u64)u << 32) | (unsigned)(0x7FFFFFFF - idx);
}
__device__ __forceinline__ void unpackkey(u64 key, float& v, int& idx) {
  unsigned u = (unsigned)(key >> 32);
  u ^= (u >> 31) ? 0x80000000u : 0xFFFFFFFFu;
  v = __uint_as_float(u);
  idx = 0x7FFFFFFF - (int)(key & 0xFFFFFFFFu);
}
__device__ __forceinline__ u64 umax64(u64 a, u64 b) { return a > b ? a : b; }
__device__ __forceinline__ u64 umin64(u64 a, u64 b) { return a > b ? b : a; }

// branchless insert of k into sorted-desc {s0..s4}
__device__ __forceinline__ void ins5(u64& s0, u64& s1, u64& s2, u64& s3, u64& s4, u64 k) {
  u64 t;
  t = umin64(s0, k); s0 = umax64(s0, k); k = t;
  t = umin64(s1, k); s1 = umax64(s1, k); k = t;
  t = umin64(s2, k); s2 = umax64(s2, k); k = t;
  t = umin64(s3, k); s3 = umax64(s3, k); k = t;
  s4 = umax64(s4, k);
}

// top-5 of two sorted-desc 5-lists (merge-path network)
__device__ __forceinline__ void merge5(u64& a0, u64& a1, u64& a2, u64& a3, u64& a4,
                                       u64 b0, u64 b1, u64 b2, u64 b3, u64 b4) {
  u64 x00 = umin64(a0, b0);
  u64 x01 = umin64(a0, b1), x10 = umin64(a1, b0);
  u64 x02 = umin64(a0, b2), x11 = umin64(a1, b1), x20 = umin64(a2, b0);
  u64 x03 = umin64(a0, b3), x12 = umin64(a1, b2), x21 = umin64(a2, b1), x30 = umin64(a3, b0);
  u64 c0 = umax64(a0, b0);
  u64 c1 = umax64(x00, umax64(a1, b1));
  u64 c2 = umax64(umax64(x01, x10), umax64(a2, b2));
  u64 c3 = umax64(umax64(x02, x20), umax64(x11, umax64(a3, b3)));
  u64 c4 = umax64(umax64(umax64(x03, x30), umax64(x12, x21)), umax64(a4, b4));
  a0 = c0; a1 = c1; a2 = c2; a3 = c3; a4 = c4;
}

__device__ __forceinline__ u64 shflx64(u64 v, int m) {
  int lo = __shfl_xor((int)(unsigned)(v & 0xFFFFFFFFull), m, 64);
  int hi = __shfl_xor((int)(unsigned)(v >> 32), m, 64);
  return ((u64)(unsigned)hi << 32) | (unsigned)lo;
}

// ---------------- graph prep ----------------
__global__ void k_deg_count(const int* __restrict__ ar, const float* __restrict__ av,
                            const int* __restrict__ nr, const float* __restrict__ nv,
                            float* deg_adj, float* deg_ned, int* cntA, int* cntN, int E) {
  int e = blockIdx.x * blockDim.x + threadIdx.x;
  if (e >= E) return;
  int ra = ar[e]; int rn = nr[e];
  atomicAdd(&deg_adj[ra], av[e]);
  atomicAdd(&deg_ned[rn], nv[e]);
  atomicAdd(&cntA[ra], 1);
  atomicAdd(&cntN[rn], 1);
}

__global__ __launch_bounds__(1024) void k_scan_pair(const int* c0, int* o0, const int* c1, int* o1, int n) {
  const int* c = (blockIdx.x == 0) ? c0 : c1;
  int* o = (blockIdx.x == 0) ? o0 : o1;
  if (c == nullptr) return;
  __shared__ int buf[1024];
  int tid = threadIdx.x;
  int base = 0;
  int chunks = (n + 1023) >> 10;
  for (int ch = 0; ch < chunks; ++ch) {
    int i = (ch << 10) + tid;
    buf[tid] = (i < n) ? c[i] : 0;
    __syncthreads();
    for (int offd = 1; offd < 1024; offd <<= 1) {
      int t = (tid >= offd) ? buf[tid - offd] : 0;
      __syncthreads();
      buf[tid] += t;
      __syncthreads();
    }
    if (i < n) o[i + 1] = base + buf[tid];
    int tot = buf[1023];
    __syncthreads();
    base += tot;
  }
  if (tid == 0) o[0] = 0;
}

__global__ void k_rs(const float* deg_adj, const float* deg_ned, float* rs_adj, float* rinv_ned, int N) {
  int i = blockIdx.x * blockDim.x + threadIdx.x;
  if (i >= N) return;
  rs_adj[i] = 1.0f / (sqrtf(deg_adj[i]) + 1e-10f);
  rinv_ned[i] = 1.0f / (deg_ned[i] + 1e-10f);
}

__global__ void k_fill2(const int* ar, const int* nr, const int* rpA, const int* rpN,
                        int* fillA, int* fillN, int* permA, int* permN, int E) {
  int e = blockIdx.x * blockDim.x + threadIdx.x;
  if (e >= E) return;
  int ra = ar[e];
  permA[rpA[ra] + atomicAdd(&fillA[ra], 1)] = e;
  int rn = nr[e];
  permN[rpN[rn] + atomicAdd(&fillN[rn], 1)] = e;
}

__global__ void k_edgeval(const int* ar, const int* ac, const float* av,
                          const int* nr, const float* nv,
                          const float* rs_adj, const float* rinv_ned,
                          float* adj_sym, float* ned_rw, int E) {
  int e = blockIdx.x * blockDim.x + threadIdx.x;
  if (e >= E) return;
  adj_sym[e] = av[e] * rs_adj[ar[e]] * rs_adj[ac[e]];
  ned_rw[e] = nv[e] * rinv_ned[nr[e]];
}

// perm-ordered (col, val) pairs: removes one indirection from SpMM inner loops
__global__ void k_permgather(const int* __restrict__ perm, const int* __restrict__ cols,
                             const float* __restrict__ vals, int2* __restrict__ out, int E) {
  int i = blockIdx.x * blockDim.x + threadIdx.x;
  if (i >= E) return;
  int id = perm[i];
  out[i] = make_int2(cols[id], __float_as_int(vals[id]));
}

// ---------------- SpMMs (CSR, block per row, feature per thread, 4x unrolled) ----------------
__global__ void k_spmm1(const int* __restrict__ rpA, const int2* __restrict__ colv,
                        const float* __restrict__ x, const float* __restrict__ Wd1,
                        float* __restrict__ emb, int N) {
  int r = blockIdx.x; int f = threadIdx.x;
  int s = rpA[r], e = rpA[r + 1];
  float acc = 0.f;
  int i = s;
  for (; i + 4 <= e; i += 4) {
    int2 c0 = colv[i], c1 = colv[i + 1], c2 = colv[i + 2], c3 = colv[i + 3];
    float v0 = x[(size_t)c0.x * F_FEAT + f];
    float v1 = x[(size_t)c1.x * F_FEAT + f];
    float v2 = x[(size_t)c2.x * F_FEAT + f];
    float v3 = x[(size_t)c3.x * F_FEAT + f];
    acc += __int_as_float(c0.y) * v0;
    acc += __int_as_float(c1.y) * v1;
    acc += __int_as_float(c2.y) * v2;
    acc += __int_as_float(c3.y) * v3;
  }
  for (; i < e; ++i) {
    int2 c0 = colv[i];
    acc += __int_as_float(c0.y) * x[(size_t)c0.x * F_FEAT + f];
  }
  emb[(size_t)r * F_FEAT + f] = tanhf(acc * Wd1[f]);
}

__global__ void k_spmm2_norm(const int* __restrict__ rpA, const int2* __restrict__ colv,
                             const float* __restrict__ emb, const float* __restrict__ Wd2,
                             float* __restrict__ embn, int N) {
  __shared__ float red[F_FEAT];
  int r = blockIdx.x; int f = threadIdx.x;
  int s = rpA[r], e = rpA[r + 1];
  float acc = 0.f;
  int i = s;
  for (; i + 4 <= e; i += 4) {
    int2 c0 = colv[i], c1 = colv[i + 1], c2 = colv[i + 2], c3 = colv[i + 3];
    float v0 = emb[(size_t)c0.x * F_FEAT + f];
    float v1 = emb[(size_t)c1.x * F_FEAT + f];
    float v2 = emb[(size_t)c2.x * F_FEAT + f];
    float v3 = emb[(size_t)c3.x * F_FEAT + f];
    acc += __int_as_float(c0.y) * v0;
    acc += __int_as_float(c1.y) * v1;
    acc += __int_as_float(c2.y) * v2;
    acc += __int_as_float(c3.y) * v3;
  }
  for (; i < e; ++i) {
    int2 c0 = colv[i];
    acc += __int_as_float(c0.y) * emb[(size_t)c0.x * F_FEAT + f];
  }
  float val = acc * Wd2[f];
  red[f] = val * val;
  __syncthreads();
  for (int st = F_FEAT / 2; st > 0; st >>= 1) {
    if (f < st) red[f] += red[f + st];
    __syncthreads();
  }
  float rinv = 1.0f / (sqrtf(red[0]) + 1e-12f);
  embn[(size_t)r * F_FEAT + f] = val * rinv;
}

__global__ void k_spmmT(const int* __restrict__ rpN, const int2* __restrict__ colv,
                        const float* __restrict__ embn, float* __restrict__ Tm, int N) {
  int r = blockIdx.x; int f = threadIdx.x;
  int s = rpN[r], e = rpN[r + 1];
  float acc = 0.f;
  int i = s;
  for (; i + 4 <= e; i += 4) {
    int2 c0 = colv[i], c1 = colv[i + 1], c2 = colv[i + 2], c3 = colv[i + 3];
    float v0 = embn[(size_t)c0.x * F_FEAT + f];
    float v1 = embn[(size_t)c1.x * F_FEAT + f];
    float v2 = embn[(size_t)c2.x * F_FEAT + f];
    float v3 = embn[(size_t)c3.x * F_FEAT + f];
    acc += __int_as_float(c0.y) * v0;
    acc += __int_as_float(c1.y) * v1;
    acc += __int_as_float(c2.y) * v2;
    acc += __int_as_float(c3.y) * v3;
  }
  for (; i < e; ++i) {
    int2 c0 = colv[i];
    acc += __int_as_float(c0.y) * embn[(size_t)c0.x * F_FEAT + f];
  }
  Tm[(size_t)r * F_FEAT + f] = acc;
}

// ---- exact 2-way fp16 split: src[N][256] f32 -> 2 planes [Npad][256] fp16 ----
__global__ void k_convert(const float* __restrict__ src,
                          unsigned short* __restrict__ p1, unsigned short* __restrict__ p2,
                          int N, int Npad) {
  int idx = blockIdx.x * blockDim.x + threadIdx.x;   // one thread per 4 elems
  int total = Npad * (F_FEAT / 4);
  if (idx >= total) return;
  int row = idx >> 6;
  int c4 = (idx & 63) << 2;
  float4 v = make_float4(0.f, 0.f, 0.f, 0.f);
  if (row < N) v = *reinterpret_cast<const float4*>(src + (size_t)row * F_FEAT + c4);
  float arr[4] = {v.x, v.y, v.z, v.w};
  ushort4 o1, o2;
  unsigned short* q1 = (unsigned short*)&o1;
  unsigned short* q2 = (unsigned short*)&o2;
#pragma unroll
  for (int j = 0; j < 4; ++j) {
    float a = arr[j];
    _Float16 h1 = (_Float16)a;
    float r = a - (float)h1;      // exact
    _Float16 h2 = (_Float16)r;
    q1[j] = __builtin_bit_cast(unsigned short, h1);
    q2[j] = __builtin_bit_cast(unsigned short, h2);
  }
  size_t off = (size_t)row * F_FEAT + c4;
  *reinterpret_cast<ushort4*>(p1 + off) = o1;
  *reinterpret_cast<ushort4*>(p2 + off) = o2;
}

// ---- MFMA GEMM (T @ embn^T strip) -> C strip; counted-vmcnt double-buffer ----
__global__ __launch_bounds__(512, 1) void k_gemm_c(
    const unsigned short* __restrict__ A1, const unsigned short* __restrict__ A2,
    const unsigned short* __restrict__ B1, const unsigned short* __restrict__ B2,
    float* __restrict__ Cbuf, int ct0) {
  __shared__ __align__(16) unsigned short lds[2 * 4 * 256 * 32];   // 128 KB

  int tid = threadIdx.x;
  int lane = tid & 63;
  int wid = tid >> 6;        // 0..7
  int wr = wid >> 2;         // 0..1  row half (128 rows)
  int wc = wid & 3;          // 0..3  col quarter (64 cols)
  int lr = lane & 15;
  int lg = lane >> 4;

  int rt = blockIdx.x;
  int ctl = blockIdx.y;            // local col tile within strip
  int ct = ct0 + ctl;
  int row0 = rt * 256, col0 = ct * 256;

  int sp = wid >> 1, sh = wid & 1;
  const unsigned short* pg = (sp == 0) ? A1 : (sp == 1) ? A2 : (sp == 2) ? B1 : B2;
  int srow = lane >> 2;
  int sslot = lane & 3;
  int sgslot = sslot ^ ((srow >> 1) & 3);
  int t0 = (sp < 2) ? row0 : col0;
  const char* gbase = (const char*)pg + ((size_t)(t0 + sh * 128 + srow) << 9) + sgslot * 16;
  char* lbase0 = (char*)lds + sp * 16384 + sh * 8192;

  int fslot = (lg ^ ((lr >> 1) & 3)) << 3;

  f32x4 acc[8][4];
#pragma unroll
  for (int m = 0; m < 8; ++m)
#pragma unroll
    for (int n = 0; n < 4; ++n) acc[m][n] = (f32x4){0.f, 0.f, 0.f, 0.f};

  // prologue: stage slab 0 -> buf0, slab 1 -> buf1 (16 loads in flight)
#pragma unroll
  for (int i = 0; i < 8; ++i)
    gload_lds16(gbase + ((size_t)i << 13), lbase0 + (i << 10));
#pragma unroll
  for (int i = 0; i < 8; ++i)
    gload_lds16(gbase + 64 + ((size_t)i << 13), lbase0 + 65536 + (i << 10));
  asm volatile("s_waitcnt vmcnt(8)" : : : "memory");   // slab0 landed
  __builtin_amdgcn_sched_barrier(0);
  __builtin_amdgcn_s_barrier();

  for (int ks = 0; ks < 8; ++ks) {
    int cur = ks & 1;
    const unsigned short* bufp = lds + cur * 32768;
    f16x8 fb[2][4];
#pragma unroll
    for (int n = 0; n < 4; ++n) {
      int off = (wc * 64 + n * 16 + lr) * 32 + fslot;
      fb[0][n] = *reinterpret_cast<const f16x8*>(bufp + 2 * 8192 + off);
      fb[1][n] = *reinterpret_cast<const f16x8*>(bufp + 3 * 8192 + off);
    }
#pragma unroll
    for (int m = 0; m < 8; ++m) {
      int off = (wr * 128 + m * 16 + lr) * 32 + fslot;
      f16x8 fa1 = *reinterpret_cast<const f16x8*>(bufp + 0 * 8192 + off);
      f16x8 fa2 = *reinterpret_cast<const f16x8*>(bufp + 1 * 8192 + off);
#pragma unroll
      for (int n = 0; n < 4; ++n) {
        acc[m][n] = __builtin_amdgcn_mfma_f32_16x16x32_f16(fa1, fb[1][n], acc[m][n], 0, 0, 0);
        acc[m][n] = __builtin_amdgcn_mfma_f32_16x16x32_f16(fa2, fb[0][n], acc[m][n], 0, 0, 0);
        acc[m][n] = __builtin_amdgcn_mfma_f32_16x16x32_f16(fa1, fb[0][n], acc[m][n], 0, 0, 0);
      }
    }
    if (ks == 7) break;    // epilogue uses registers only

    // my LDS reads of buf[cur] done -> after barrier, buf[cur] is free to overwrite
    asm volatile("s_waitcnt lgkmcnt(0)" : : : "memory");
    __builtin_amdgcn_sched_barrier(0);
    __builtin_amdgcn_s_barrier();

    if (ks < 6) {          // stage slab ks+2 into buf[cur]; keep 8 loads in flight
      const char* g = gbase + (size_t)(ks + 2) * 64;
      char* lb = lbase0 + (cur << 16);
#pragma unroll
      for (int i = 0; i < 8; ++i)
        gload_lds16(g + ((size_t)i << 13), lb + (i << 10));
      asm volatile("s_waitcnt vmcnt(8)" : : : "memory");   // slab ks+1 landed
    } else {               // ks == 6: no more staging; drain slab 7
      asm volatile("s_waitcnt vmcnt(0)" : : : "memory");
    }
    __builtin_amdgcn_sched_barrier(0);
    __builtin_amdgcn_s_barrier();   // all waves' next slab landed
  }

#pragma unroll
  for (int m = 0; m < 8; ++m) {
#pragma unroll
    for (int rg = 0; rg < 4; ++rg) {
      int rl = wr * 128 + m * 16 + lg * 4 + rg;
      float* cr = Cbuf + (size_t)(row0 + rl) * STRIPW + ctl * 256 + wc * 64 + lr;
#pragma unroll
      for (int n = 0; n < 4; ++n) cr[n * 16] = acc[m][n][rg];
    }
  }
}

// ---- strip-wise per-row top-5: branchless u64-key scan + merge-path butterfly ----
__global__ __launch_bounds__(256) void k_topk(const float* __restrict__ Cbuf, int col0, int first,
                                              u64* __restrict__ Kst, int N) {
  int wid = threadIdx.x >> 6, lane = threadIdx.x & 63;
  int r = blockIdx.x * 4 + wid;
  if (r >= N) return;
  const float4* rowp = reinterpret_cast<const float4*>(Cbuf + (size_t)r * STRIPW);
  float4 vv[SCT];
#pragma unroll
  for (int j = 0; j < SCT; ++j) vv[j] = rowp[j * 64 + lane];   // independent, issued early

  u64 s0 = 0, s1 = 0, s2 = 0, s3 = 0, s4 = 0;
#pragma unroll
  for (int j = 0; j < SCT; ++j) {
    int cb = col0 + (j * 64 + lane) * 4;
    float arr[4] = {vv[j].x, vv[j].y, vv[j].z, vv[j].w};
#pragma unroll
    for (int q = 0; q < 4; ++q) {
      int gc = cb + q;
      u64 key = (gc < N) ? packkey(arr[q], gc) : 0ull;
      ins5(s0, s1, s2, s3, s4, key);
    }
  }
#pragma unroll
  for (int d = 1; d < 64; d <<= 1) {
    u64 t0 = shflx64(s0, d), t1 = shflx64(s1, d), t2 = shflx64(s2, d),
        t3 = shflx64(s3, d), t4 = shflx64(s4, d);
    merge5(s0, s1, s2, s3, s4, t0, t1, t2, t3, t4);
  }
  if (lane == 0) {
    u64* st = Kst + (size_t)r * 5;
    if (!first) merge5(s0, s1, s2, s3, s4, st[0], st[1], st[2], st[3], st[4]);
    st[0] = s0; st[1] = s1; st[2] = s2; st[3] = s3; st[4] = s4;
  }
}

// ---------------- unpack + degrees/counts from final top-5 ----------------
__global__ void k_merge(const u64* __restrict__ Kst,
                        float* __restrict__ topv, int* __restrict__ topi,
                        const float* deg_adj, float* deg_new, const int* cntA, int* cnt_new, int N) {
  int r = blockIdx.x * blockDim.x + threadIdx.x;
  if (r >= N) return;
  float sumv = 0.f;
  for (int k = 0; k < 5; ++k) {
    float v; int ix;
    unpackkey(Kst[(size_t)r * 5 + k], v, ix);
    topv[(size_t)r * 5 + k] = v;
    topi[(size_t)r * 5 + k] = ix;
    sumv += v;
    atomicAdd(&deg_new[ix], v);
    atomicAdd(&cnt_new[ix], 1);
  }
  atomicAdd(&deg_new[r], deg_adj[r] + sumv);
  atomicAdd(&cnt_new[r], cntA[r] + KTOP);
}

__global__ void k_rs_new(const float* deg_new, float* rs_new, int N) {
  int i = blockIdx.x * blockDim.x + threadIdx.x;
  if (i >= N) return;
  rs_new[i] = 1.0f / (sqrtf(deg_new[i]) + 1e-10f);
}

// build new-graph CSR payload directly: colv_new[pos] = (col, val * rs[col])
__global__ void k_fill_new(const int* __restrict__ ar, const int* __restrict__ ac,
                           const float* __restrict__ av,
                           const int* __restrict__ topi, const float* __restrict__ topv,
                           const float* __restrict__ rs_new,
                           const int* __restrict__ rp_new, int* fill_new,
                           int2* __restrict__ colv_new, int E, int NK, int total) {
  int t = blockIdx.x * blockDim.x + threadIdx.x;
  if (t >= total) return;
  int r, c; float v;
  if (t < E)            { r = ar[t]; c = ac[t]; v = av[t]; }
  else if (t < E + NK)  { int q = t - E; r = q / KTOP; c = topi[q]; v = topv[q]; }
  else                  { int q = t - E - NK; r = topi[q]; c = q / KTOP; v = topv[q]; }
  int pos = rp_new[r] + atomicAdd(&fill_new[r], 1);
  colv_new[pos] = make_int2(c, __float_as_int(v * rs_new[c]));
}

// ---------------- dense layers ----------------
__global__ void k_xw1(const float* __restrict__ x, const float* __restrict__ W1,
                      float* __restrict__ XW1, int N) {
  int c = threadIdx.x & 127;
  int half = threadIdx.x >> 7;
  int r0 = blockIdx.x * 8 + half * 4;
  int rm = N - 1;
  const float* x0 = x + (size_t)min(r0 + 0, rm) * F_FEAT;
  const float* x1 = x + (size_t)min(r0 + 1, rm) * F_FEAT;
  const float* x2 = x + (size_t)min(r0 + 2, rm) * F_FEAT;
  const float* x3 = x + (size_t)min(r0 + 3, rm) * F_FEAT;
  float a0 = 0.f, a1 = 0.f, a2 = 0.f, a3 = 0.f;
  for (int k = 0; k < F_FEAT; ++k) {
    float wv = W1[k * NHID + c];
    a0 += x0[k] * wv; a1 += x1[k] * wv; a2 += x2[k] * wv; a3 += x3[k] * wv;
  }
  if (r0 + 0 < N) XW1[(size_t)(r0 + 0) * NHID + c] = a0;
  if (r0 + 1 < N) XW1[(size_t)(r0 + 1) * NHID + c] = a1;
  if (r0 + 2 < N) XW1[(size_t)(r0 + 2) * NHID + c] = a2;
  if (r0 + 3 < N) XW1[(size_t)(r0 + 3) * NHID + c] = a3;
}

__global__ void k_spmm_h(const int* __restrict__ rp, const int2* __restrict__ colv,
                         const float* __restrict__ rs, const float* __restrict__ XW1,
                         const float* __restrict__ b1, float* __restrict__ h, int N) {
  int r = blockIdx.x; int f = threadIdx.x;  // 128 threads
  int s = rp[r], e = rp[r + 1];
  float acc = 0.f;
  int i = s;
  for (; i + 4 <= e; i += 4) {
    int2 c0 = colv[i], c1 = colv[i + 1], c2 = colv[i + 2], c3 = colv[i + 3];
    float v0 = XW1[(size_t)c0.x * NHID + f];
    float v1 = XW1[(size_t)c1.x * NHID + f];
    float v2 = XW1[(size_t)c2.x * NHID + f];
    float v3 = XW1[(size_t)c3.x * NHID + f];
    acc += __int_as_float(c0.y) * v0;
    acc += __int_as_float(c1.y) * v1;
    acc += __int_as_float(c2.y) * v2;
    acc += __int_as_float(c3.y) * v3;
  }
  for (; i < e; ++i) {
    int2 c0 = colv[i];
    acc += __int_as_float(c0.y) * XW1[(size_t)c0.x * NHID + f];
  }
  float o = rs[r] * acc + b1[f];
  h[(size_t)r * NHID + f] = fmaxf(o, 0.f);
}

__global__ void k_hw2(const float* __restrict__ h, const float* __restrict__ W2,
                      float* __restrict__ HW2, int N) {
  int tid = threadIdx.x;
  int rr = tid >> 4, c = tid & 15;
  int r = blockIdx.x * 16 + rr;
  if (r >= N) return;
  float acc = 0.f;
  for (int k = 0; k < NHID; ++k) acc += h[(size_t)r * NHID + k] * W2[k * NCLASS + c];
  HW2[(size_t)r * NCLASS + c] = acc;
}

__global__ void k_spmm_out(const int* __restrict__ rp, const int2* __restrict__ colv,
                           const float* __restrict__ rs, const float* __restrict__ HW2,
                           const float* __restrict__ b2, float* __restrict__ out, int N) {
  int tid = threadIdx.x;
  int rr = tid >> 4, c = tid & 15;
  int r = blockIdx.x * 16 + rr;
  if (r >= N) return;
  int s = rp[r], e = rp[r + 1];
  float acc = 0.f;
  int i = s;
  for (; i + 4 <= e; i += 4) {
    int2 c0 = colv[i], c1 = colv[i + 1], c2 = colv[i + 2], c3 = colv[i + 3];
    float v0 = HW2[(size_t)c0.x * NCLASS + c];
    float v1 = HW2[(size_t)c1.x * NCLASS + c];
    float v2 = HW2[(size_t)c2.x * NCLASS + c];
    float v3 = HW2[(size_t)c3.x * NCLASS + c];
    acc += __int_as_float(c0.y) * v0;
    acc += __int_as_float(c1.y) * v1;
    acc += __int_as_float(c2.y) * v2;
    acc += __int_as_float(c3.y) * v3;
  }
  for (; i < e; ++i) {
    int2 c0 = colv[i];
    acc += __int_as_float(c0.y) * HW2[(size_t)c0.x * NCLASS + c];
  }
  out[(size_t)r * NCLASS + c] = rs[r] * acc + b2[c];
}

// ---------------- host ----------------
extern "C" void kernel_launch(void* const* d_in, const int* in_sizes, int n_in,
                              void* d_out, int out_size, void* d_ws, size_t ws_size,
                              hipStream_t stream) {
  (void)n_in; (void)out_size; (void)ws_size;
  const float* x   = (const float*)d_in[0];
  const int*   ar  = (const int*)d_in[1];
  const int*   ac  = (const int*)d_in[2];
  const float* av  = (const float*)d_in[3];
  const int*   nr  = (const int*)d_in[4];
  const int*   nc  = (const int*)d_in[5];
  const float* nv  = (const float*)d_in[6];
  const float* Wd1 = (const float*)d_in[7];
  const float* Wd2 = (const float*)d_in[8];
  const float* W1  = (const float*)d_in[9];
  const float* b1  = (const float*)d_in[10];
  const float* W2  = (const float*)d_in[11];
  const float* b2  = (const float*)d_in[12];
  int N = in_sizes[0] / F_FEAT;
  int E = in_sizes[3];
  int NK = N * KTOP;
  int total_new = E + 2 * NK;
  int Npad = ((N + 255) / 256) * 256;
  int nrt = Npad / 256;
  int nct = nrt;
  int nstrip = (nct + SCT - 1) / SCT;

  char* w = (char*)d_ws;
  size_t off = 0;
  auto carveB = [&](size_t bytes) -> void* {
    void* p = (void*)(w + off);
    off += (bytes + 255) & ~((size_t)255);
    return p;
  };
  auto carve = [&](size_t elems) -> void* { return carveB(elems * 4); };
  size_t zstart = off;
  float* deg_adj = (float*)carve(N);
  float* deg_ned = (float*)carve(N);
  float* deg_new = (float*)carve(N);
  int* cntA = (int*)carve(N);
  int* cntN = (int*)carve(N);
  int* cnt_new = (int*)carve(N);
  int* fillA = (int*)carve(N);
  int* fillN = (int*)carve(N);
  int* fill_new = (int*)carve(N);
  size_t zbytes = off - zstart;
  float* rs_adj = (float*)carve(N);
  float* rinv_ned = (float*)carve(N);
  float* rs_new = (float*)carve(N);
  float* adj_sym = (float*)carve(E);
  float* ned_rw = (float*)carve(E);
  int* rpA = (int*)carve(N + 1);
  int* rpN = (int*)carve(N + 1);
  int* rp_new = (int*)carve(N + 1);
  int* permA = (int*)carve(E);
  int* permN = (int*)carve(E);
  int2* colvA = (int2*)carveB((size_t)E * 8);
  int2* colvN = (int2*)carveB((size_t)E * 8);
  int2* colv_new = (int2*)carveB((size_t)total_new * 8);
  float* emb  = (float*)carve((size_t)N * F_FEAT);
  float* embn = (float*)carve((size_t)N * F_FEAT);
  float* Tm   = (float*)carve((size_t)N * F_FEAT);
  float* topv = (float*)carve(NK);
  int*   topi = (int*)carve(NK);
  u64*   Kst  = (u64*)carveB((size_t)NK * 8);
  float* XW1  = (float*)carve((size_t)N * NHID);
  float* hbuf = (float*)carve((size_t)N * NHID);
  float* HW2  = (float*)carve((size_t)N * NCLASS);
  size_t planeBytes = (size_t)Npad * F_FEAT * 2;
  unsigned short* TA1 = (unsigned short*)carveB(planeBytes);
  unsigned short* TA2 = (unsigned short*)carveB(planeBytes);
  unsigned short* EB1 = (unsigned short*)carveB(planeBytes);
  unsigned short* EB2 = (unsigned short*)carveB(planeBytes);
  float* Cbuf = (float*)carveB((size_t)Npad * STRIPW * 4);

  hipMemsetAsync(w + zstart, 0, zbytes, stream);

  int eb = (E + 255) / 256;
  k_deg_count<<<eb, 256, 0, stream>>>(ar, av, nr, nv, deg_adj, deg_ned, cntA, cntN, E);
  k_scan_pair<<<2, 1024, 0, stream>>>(cntA, rpA, cntN, rpN, N);
  k_rs<<<(N + 255) / 256, 256, 0, stream>>>(deg_adj, deg_ned, rs_adj, rinv_ned, N);
  k_fill2<<<eb, 256, 0, stream>>>(ar, nr, rpA, rpN, fillA, fillN, permA, permN, E);
  k_edgeval<<<eb, 256, 0, stream>>>(ar, ac, av, nr, nv, rs_adj, rinv_ned, adj_sym, ned_rw, E);
  k_permgather<<<eb, 256, 0, stream>>>(permA, ac, adj_sym, colvA, E);
  k_permgather<<<eb, 256, 0, stream>>>(permN, nc, ned_rw, colvN, E);
  k_spmm1<<<N, F_FEAT, 0, stream>>>(rpA, colvA, x, Wd1, emb, N);
  k_spmm2_norm<<<N, F_FEAT, 0, stream>>>(rpA, colvA, emb, Wd2, embn, N);
  k_spmmT<<<N, F_FEAT, 0, stream>>>(rpN, colvN, embn, Tm, N);
  int cvb = (Npad * (F_FEAT / 4) + 255) / 256;
  k_convert<<<cvb, 256, 0, stream>>>(Tm, TA1, TA2, N, Npad);
  k_convert<<<cvb, 256, 0, stream>>>(embn, EB1, EB2, N, Npad);

  for (int s = 0; s < nstrip; ++s) {
    dim3 gg(nrt, SCT);
    k_gemm_c<<<gg, 512, 0, stream>>>(TA1, TA2, EB1, EB2, Cbuf, s * SCT);
    k_topk<<<(N + 3) / 4, 256, 0, stream>>>(Cbuf, s * STRIPW, (s == 0) ? 1 : 0, Kst, N);
  }

  k_merge<<<(N + 255) / 256, 256, 0, stream>>>(Kst, topv, topi, deg_adj, deg_new, cntA, cnt_new, N);
  k_scan_pair<<<1, 1024, 0, stream>>>(cnt_new, rp_new, nullptr, nullptr, N);
  k_rs_new<<<(N + 255) / 256, 256, 0, stream>>>(deg_new, rs_new, N);
  k_fill_new<<<(total_new + 255) / 256, 256, 0, stream>>>(ar, ac, av, topi, topv, rs_new,
                                                          rp_new, fill_new, colv_new, E, NK, total_new);
  k_xw1<<<(N + 7) / 8, 256, 0, stream>>>(x, W1, XW1, N);
  k_spmm_h<<<N, NHID, 0, stream>>>(rp_new, colv_new, rs_new, XW1, b1, hbuf, N);
  k_hw2<<<(N + 15) / 16, 256, 0, stream>>>(hbuf, W2, HW2, N);
  k_spmm_out<<<(N + 15) / 16, 256, 0, stream>>>(rp_new, colv_new, rs_new, HW2, b2, (float*)d_out, N);
}